// Round 13
// baseline (103.422 us; speedup 1.0000x reference)
//
#include <hip/hip_runtime.h>
#include <hip/hip_bf16.h>
#include <math.h>

// ScreeningAttention: B=2, T=2048, D_MODEL=768, H=12, D=64
// Round 13 = round-11 base (89.5us) with k_attn re-balanced:
//   all 12672 (bh,qt,kt) key-tiles flattened; 768 blocks x 16-17 tiles each
//   (uniform duration -> no occupancy decay tail). Rows split across <=3
//   strips accumulate into f32 partials (deterministic slots, no atomics);
//   k_tanh sums partials + TanhNorm -> attn bf16.
// k_cvt -> k_proj (dbuf GEMM) -> k_attn (strip tiles) -> k_tanh -> k_outproj.
// NOTE: v_cvt_pk_bf16_f32 inline-asm packing was a correctness bug (r4/6/7);
// bit-manip RNE is the proven path. A-direct/fused-cvt in k_proj regressed
// (r10: uncoalesced frag loads; r12: serial cvt path) -- keep split k_cvt.

typedef __attribute__((ext_vector_type(8))) short short8;     // 8 bf16, MFMA A/B frag
typedef __attribute__((ext_vector_type(4))) float f32x4;      // MFMA C/D frag
typedef __attribute__((ext_vector_type(4))) unsigned int uint4v;
typedef __attribute__((ext_vector_type(2))) unsigned int uint2v;
typedef __attribute__((ext_vector_type(4))) float float4v;

#define MFMA_BF16(a, b, c) __builtin_amdgcn_mfma_f32_16x16x32_bf16((a), (b), (c), 0, 0, 0)

// round-to-nearest-even f32->bf16, bit-manip (round-3-proven).
static __device__ __forceinline__ unsigned short f2bf(float f) {
  union { float f; unsigned u; } v; v.f = f;
  unsigned r = v.u + 0x7FFFu + ((v.u >> 16) & 1u);
  return (unsigned short)(r >> 16);
}
static __device__ __forceinline__ unsigned pack2(float a, float b) {
  return (unsigned)f2bf(a) | ((unsigned)f2bf(b) << 16);
}
// async global->LDS, 16B per lane. LDS dest = wave-uniform base + lane*16.
static __device__ __forceinline__ void gload_lds16(const void* g, void* l) {
  __builtin_amdgcn_global_load_lds((const __attribute__((address_space(1))) unsigned int*)g,
                                   (__attribute__((address_space(3))) unsigned int*)l, 16, 0, 0);
}
// strip mapping: block s covers tiles [f(s), f(s+1)),
// f(s) = s<384 ? 17*s : 6528 + 16*(s-384); strip_of is the inverse.
static __device__ __forceinline__ int strip_first(int s) {
  return (s < 384) ? s * 17 : 6528 + (s - 384) * 16;
}
static __device__ __forceinline__ int strip_of(int g) {
  return (g < 6528) ? g / 17 : 384 + (g - 6528) / 16;
}

// ---------------------------------------------------------------------------
// Kernel 0: convert Xq,Xk,Xv (3x3145728) + Wq,Wk,Wv,Wo (4x589824) f32->bf16
// into one contiguous bf16 region. grid 5760x256, 8 elems/thread.
// ---------------------------------------------------------------------------
__global__ __launch_bounds__(256) void k_cvt(
    const float* __restrict__ s0, const float* __restrict__ s1, const float* __restrict__ s2,
    const float* __restrict__ s3, const float* __restrict__ s4, const float* __restrict__ s5,
    const float* __restrict__ s6, unsigned short* __restrict__ dst) {
  const size_t e = ((size_t)blockIdx.x * 256 + threadIdx.x) * 8;
  const float* src;
  size_t off;
  if (e < 9437184) {
    const int i = (int)(e / 3145728);
    src = (i == 0) ? s0 : (i == 1) ? s1 : s2;
    off = e - (size_t)i * 3145728;
  } else {
    const size_t ew = e - 9437184;
    const int i = (int)(ew / 589824);
    src = (i == 0) ? s3 : (i == 1) ? s4 : (i == 2) ? s5 : s6;
    off = ew - (size_t)i * 589824;
  }
  const float4v f0 = *(const float4v*)(src + off);
  const float4v f1 = *(const float4v*)(src + off + 4);
  uint4v u = {pack2(f0.x, f0.y), pack2(f0.z, f0.w), pack2(f1.x, f1.y), pack2(f1.z, f1.w)};
  *(uint4v*)(dst + e) = u;
}

// ---------------------------------------------------------------------------
// Kernel 1: QKV projection (bf16 inputs) + per-head l2 normalization.
// (round-11 proven, unchanged) 128x128 tile, dbuf gload_lds, XOR swizzle.
// which==2 (V) writes TRANSPOSED to vtb [bh][d][t]. grid (32,6,3); block 256.
// ---------------------------------------------------------------------------
__global__ __launch_bounds__(256) void k_proj(
    const unsigned short* __restrict__ Xb, const unsigned short* __restrict__ Wb,
    unsigned short* __restrict__ qb, unsigned short* __restrict__ kb,
    unsigned short* __restrict__ vtb) {
  __shared__ alignas(16) unsigned char smem[65536];
  float* o_s = (float*)smem;
  unsigned short* vt_s = (unsigned short*)smem;

  const int which = blockIdx.z;
  const unsigned short* X = Xb + (size_t)which * 3145728;
  const unsigned short* W = Wb + (size_t)which * 589824;

  const int mbase = blockIdx.x * 128;
  const int nb = blockIdx.y;
  const int tid = threadIdx.x;
  const int lane = tid & 63;
  const int wv = tid >> 6;
  const int wm = wv >> 1, wn = wv & 1;
  const int l15 = lane & 15, l4 = lane >> 4;
  const int srow8 = lane >> 3;
  const int schunk = (lane & 7) ^ srow8;

  f32x4 acc[4][4];
#pragma unroll
  for (int m = 0; m < 4; ++m)
#pragma unroll
    for (int n = 0; n < 4; ++n) acc[m][n] = (f32x4){0.f, 0.f, 0.f, 0.f};

#pragma unroll
  for (int i = 0; i < 4; ++i) {
    const int j = wv * 4 + i;
    gload_lds16(X + (size_t)(mbase + j * 8 + srow8) * 768 + schunk * 8, smem + j * 1024);
    gload_lds16(W + (size_t)(nb * 128 + j * 8 + srow8) * 768 + schunk * 8,
                smem + 16384 + j * 1024);
  }

  for (int ks = 0; ks < 12; ++ks) {
    const int cur = (ks & 1) * 32768;
    asm volatile("s_waitcnt vmcnt(0)" ::: "memory");
    __builtin_amdgcn_sched_barrier(0);
    __builtin_amdgcn_s_barrier();
    __builtin_amdgcn_sched_barrier(0);
    if (ks < 11) {
      const int nxt = ((ks + 1) & 1) * 32768;
      const int k0n = (ks + 1) * 64;
#pragma unroll
      for (int i = 0; i < 4; ++i) {
        const int j = wv * 4 + i;
        gload_lds16(X + (size_t)(mbase + j * 8 + srow8) * 768 + k0n + schunk * 8,
                    smem + nxt + j * 1024);
        gload_lds16(W + (size_t)(nb * 128 + j * 8 + srow8) * 768 + k0n + schunk * 8,
                    smem + nxt + 16384 + j * 1024);
      }
      __builtin_amdgcn_sched_barrier(0);
    }
    __builtin_amdgcn_s_setprio(1);
#pragma unroll
    for (int kc = 0; kc < 2; ++kc) {
      const int cx = (kc << 2) | l4;
      short8 ar[4], br[4];
#pragma unroll
      for (int m = 0; m < 4; ++m) {
        const int r = wm * 64 + m * 16 + l15;
        ar[m] = *(const short8*)(smem + cur + r * 128 + ((cx ^ (r & 7)) << 4));
      }
#pragma unroll
      for (int n = 0; n < 4; ++n) {
        const int r = wn * 64 + n * 16 + l15;
        br[n] = *(const short8*)(smem + cur + 16384 + r * 128 + ((cx ^ (r & 7)) << 4));
      }
#pragma unroll
      for (int m = 0; m < 4; ++m)
#pragma unroll
        for (int n = 0; n < 4; ++n) acc[m][n] = MFMA_BF16(ar[m], br[n], acc[m][n]);
    }
    __builtin_amdgcn_s_setprio(0);
  }

  const int b = mbase >> 11;
  const int tbase = mbase & 2047;
  const int row2 = tid >> 1, half = tid & 1;
  for (int p = 0; p < 2; ++p) {
    __syncthreads();
    if (wn == p) {
#pragma unroll
      for (int m = 0; m < 4; ++m)
#pragma unroll
        for (int n = 0; n < 4; ++n)
#pragma unroll
          for (int j = 0; j < 4; ++j)
            o_s[(wm * 64 + m * 16 + l4 * 4 + j) * 68 + n * 16 + l15] = acc[m][n][j];
    }
    __syncthreads();
    float v[32];
    float ss = 0.f;
#pragma unroll
    for (int c = 0; c < 8; ++c) {
      float4v f = *(const float4v*)(o_s + row2 * 68 + half * 32 + c * 4);
      v[c * 4 + 0] = f.x; v[c * 4 + 1] = f.y; v[c * 4 + 2] = f.z; v[c * 4 + 3] = f.w;
      ss += f.x * f.x + f.y * f.y + f.z * f.z + f.w * f.w;
    }
    ss += __shfl_xor(ss, 1);
    const float inv = 1.f / fmaxf(sqrtf(ss), 1e-8f);
    const int h = nb * 2 + p, bh = b * 12 + h;
    if (which < 2) {
      unsigned short* outp =
          ((which == 0) ? qb : kb) + ((size_t)bh * 2048 + tbase + row2) * 64 + half * 32;
#pragma unroll
      for (int c = 0; c < 4; ++c) {
        uint4v o = {pack2(v[c * 8 + 0] * inv, v[c * 8 + 1] * inv),
                    pack2(v[c * 8 + 2] * inv, v[c * 8 + 3] * inv),
                    pack2(v[c * 8 + 4] * inv, v[c * 8 + 5] * inv),
                    pack2(v[c * 8 + 6] * inv, v[c * 8 + 7] * inv)};
        *(uint4v*)(outp + c * 8) = o;
      }
      __syncthreads();
    } else {
      __syncthreads();
#pragma unroll
      for (int c = 0; c < 32; ++c)
        vt_s[(half * 32 + c) * 136 + row2] = f2bf(v[c] * inv);
      __syncthreads();
      const int d = tid >> 2, tc = (tid & 3) * 32;
      unsigned short* dst = vtb + ((size_t)bh * 64 + d) * 2048 + tbase + tc;
#pragma unroll
      for (int c = 0; c < 4; ++c)
        *(uint4v*)(dst + c * 8) = *(const uint4v*)(vt_s + d * 136 + tc + c * 8);
      __syncthreads();
    }
  }
}

// ---------------------------------------------------------------------------
// Kernel 2: causal screening attention, STRIP-TILED.
// 768 blocks x exactly 16-17 (bh,qt,kt) tiles each (uniform duration).
// Per tile: proven dbuf schedule {vmcnt(0)+barrier -> prefetch g+1 -> S^T MFMA
// -> alpha -> p_s -> lgkm+barrier -> PV}. At each row (bh,qt) boundary the
// 64x64 f32 O-partial is flushed to partials[slot] (slot = strip ordinal in
// row, <=3, deterministic); Q frags reloaded for the next row.
// LDS: K0@0 K1@8192 V0@16384 V1@24576 p_s@32768 (9216). block 256 (4 waves).
// ---------------------------------------------------------------------------
__global__ __launch_bounds__(256) void k_attn(
    const unsigned short* __restrict__ qb, const unsigned short* __restrict__ kb,
    const unsigned short* __restrict__ vtb, const float* __restrict__ s_v,
    const float* __restrict__ s_r, float* __restrict__ partials) {
  __shared__ alignas(16) unsigned char smem[41984];
  unsigned short* p_s = (unsigned short*)(smem + 32768);  // [64 q][72 key] bf16

  const int s = blockIdx.x;
  const int gs = strip_first(s);
  const int ge = strip_first(s + 1);

  // decode gs -> (bh, qt, kt)
  int bh = gs / 528;
  int ii = gs - bh * 528;
  int qt = (int)((sqrtf(8.f * (float)ii + 1.f) - 1.f) * 0.5f);
  while ((qt + 1) * (qt + 2) / 2 <= ii) ++qt;
  while (qt * (qt + 1) / 2 > ii) --qt;
  int kt = ii - qt * (qt + 1) / 2;

  const int tid = threadIdx.x;
  const int lane = tid & 63;
  const int wv = tid >> 6;
  const int wm = wv >> 1, wn = wv & 1;  // S: wm=keys, wn=q. PV: wm=d, wn=q.
  const int l15 = lane & 15, l4 = lane >> 4;
  const int srow8 = lane >> 3;
  const int schunk = (lane & 7) ^ srow8;

  // prologue: issue K/V gloads for tile gs into buf 0
  {
    const unsigned short* Kp = kb + (size_t)bh * 131072;
    const unsigned short* VTp = vtb + (size_t)bh * 131072;
    const int kbase = kt * 64;
#pragma unroll
    for (int i = 0; i < 2; ++i) {
      const int j = wv * 2 + i;
      gload_lds16(Kp + (size_t)(kbase + j * 8 + srow8) * 64 + schunk * 8, smem + j * 1024);
      gload_lds16(VTp + (size_t)(j * 8 + srow8) * 2048 + kbase + schunk * 8,
                  smem + 16384 + j * 1024);
    }
  }

  // per-row state: head params + Q fragments (B-operand of swapped S)
  float w_h = expf(s_v[bh % 12]) + 1.0f;
  float lr_h = log2f(expf(s_r[bh % 12]) + 1.0f);
  short8 qf[2][2];
  {
    const unsigned short* Qp = qb + (size_t)bh * 131072;
    const int qbase = qt * 64;
#pragma unroll
    for (int n = 0; n < 2; ++n)
#pragma unroll
      for (int kc = 0; kc < 2; ++kc)
        qf[n][kc] = *(const short8*)(Qp + (size_t)(qbase + wn * 32 + n * 16 + l15) * 64 +
                                     kc * 32 + l4 * 8);
  }

  f32x4 acc_o[2][2];  // [qi][di]
#pragma unroll
  for (int m = 0; m < 2; ++m)
#pragma unroll
    for (int n = 0; n < 2; ++n) acc_o[m][n] = (f32x4){0.f, 0.f, 0.f, 0.f};

  for (int g = gs; g < ge; ++g) {
    const int cur = ((g - gs) & 1) * 8192;
    const int qbase = qt * 64;
    // wait this tile's K/V (the only outstanding prefetch), sync
    asm volatile("s_waitcnt vmcnt(0)" ::: "memory");
    __builtin_amdgcn_sched_barrier(0);
    __builtin_amdgcn_s_barrier();
    __builtin_amdgcn_sched_barrier(0);
    // next tile coords
    int bh2 = bh, qt2 = qt, kt2 = kt + 1;
    if (kt2 > qt2) {
      kt2 = 0;
      ++qt2;
      if (qt2 == 32) { qt2 = 0; ++bh2; }
    }
    // prefetch tile g+1 into the other buffer
    if (g + 1 < ge) {
      const int nxt = ((g + 1 - gs) & 1) * 8192;
      const unsigned short* Kp2 = kb + (size_t)bh2 * 131072;
      const unsigned short* VTp2 = vtb + (size_t)bh2 * 131072;
      const int kb2 = kt2 * 64;
#pragma unroll
      for (int i = 0; i < 2; ++i) {
        const int j = wv * 2 + i;
        gload_lds16(Kp2 + (size_t)(kb2 + j * 8 + srow8) * 64 + schunk * 8, smem + nxt + j * 1024);
        gload_lds16(VTp2 + (size_t)(j * 8 + srow8) * 2048 + kb2 + schunk * 8,
                    smem + 16384 + nxt + j * 1024);
      }
      __builtin_amdgcn_sched_barrier(0);  // pin prefetch issue before compute
    }
    // S^T = K Q^T : rows = keys, cols = q
    f32x4 s_acc[2][2];
#pragma unroll
    for (int m = 0; m < 2; ++m)
#pragma unroll
      for (int n = 0; n < 2; ++n) s_acc[m][n] = (f32x4){0.f, 0.f, 0.f, 0.f};
    __builtin_amdgcn_s_setprio(1);
#pragma unroll
    for (int kc = 0; kc < 2; ++kc) {
      const int cx = (kc << 2) | l4;
      const int r0 = wm * 32 + l15, r1 = wm * 32 + 16 + l15;
      short8 a0 = *(const short8*)(smem + cur + r0 * 128 + ((cx ^ (r0 & 7)) << 4));
      short8 a1 = *(const short8*)(smem + cur + r1 * 128 + ((cx ^ (r1 & 7)) << 4));
      s_acc[0][0] = MFMA_BF16(a0, qf[0][kc], s_acc[0][0]);
      s_acc[0][1] = MFMA_BF16(a0, qf[1][kc], s_acc[0][1]);
      s_acc[1][0] = MFMA_BF16(a1, qf[0][kc], s_acc[1][0]);
      s_acc[1][1] = MFMA_BF16(a1, qf[1][kc], s_acc[1][1]);
    }
    __builtin_amdgcn_s_setprio(0);
    // alpha = r * clamp((s+1)/2)^w ; frag reg-dim = consecutive keys -> b64 stores
    const bool diag = (kt == qt);
#pragma unroll
    for (int m = 0; m < 2; ++m)
#pragma unroll
      for (int n = 0; n < 2; ++n) {
        const int lkb = wm * 32 + m * 16 + l4 * 4;
        const int lq = wn * 32 + n * 16 + l15;
        float av[4];
#pragma unroll
        for (int t = 0; t < 4; ++t) {
          const float base = __builtin_amdgcn_fmed3f(fmaf(s_acc[m][n][t], 0.5f, 0.5f), 0.f, 1.f);
          float a = __builtin_amdgcn_exp2f(fmaf(w_h, __builtin_amdgcn_logf(base), lr_h));
          if (diag && (lkb + t) > lq) a = 0.f;
          av[t] = a;
        }
        uint2v u = {pack2(av[0], av[1]), pack2(av[2], av[3])};
        *(uint2v*)(p_s + lq * 72 + lkb) = u;
      }
    asm volatile("s_waitcnt lgkmcnt(0)" ::: "memory");
    __builtin_amdgcn_sched_barrier(0);
    __builtin_amdgcn_s_barrier();
    __builtin_amdgcn_sched_barrier(0);
    // O += P V
    __builtin_amdgcn_s_setprio(1);
#pragma unroll
    for (int kc = 0; kc < 2; ++kc) {
      const int cx = (kc << 2) | l4;
      const int r0 = wm * 32 + l15, r1 = wm * 32 + 16 + l15;
      short8 pa0 = *(const short8*)(p_s + (wn * 32 + l15) * 72 + kc * 32 + l4 * 8);
      short8 pa1 = *(const short8*)(p_s + (wn * 32 + 16 + l15) * 72 + kc * 32 + l4 * 8);
      short8 vb0 = *(const short8*)(smem + 16384 + cur + r0 * 128 + ((cx ^ (r0 & 7)) << 4));
      short8 vb1 = *(const short8*)(smem + 16384 + cur + r1 * 128 + ((cx ^ (r1 & 7)) << 4));
      acc_o[0][0] = MFMA_BF16(pa0, vb0, acc_o[0][0]);
      acc_o[0][1] = MFMA_BF16(pa0, vb1, acc_o[0][1]);
      acc_o[1][0] = MFMA_BF16(pa1, vb0, acc_o[1][0]);
      acc_o[1][1] = MFMA_BF16(pa1, vb1, acc_o[1][1]);
    }
    __builtin_amdgcn_s_setprio(0);
    // row boundary (or strip end): flush partial O, reset, reload row state
    if (diag || (g + 1 == ge)) {
      const int g0 = bh * 528 + qt * (qt + 1) / 2;
      const int slot = s - strip_of(g0);
      float* pb = partials + (((size_t)slot * 24 + bh) * 2048 + qbase) * 64;
#pragma unroll
      for (int qi = 0; qi < 2; ++qi)
#pragma unroll
        for (int di = 0; di < 2; ++di)
#pragma unroll
          for (int j = 0; j < 4; ++j)
            pb[(size_t)(wn * 32 + qi * 16 + l4 * 4 + j) * 64 + wm * 32 + di * 16 + l15] =
                acc_o[qi][di][j];
#pragma unroll
      for (int m = 0; m < 2; ++m)
#pragma unroll
        for (int n = 0; n < 2; ++n) acc_o[m][n] = (f32x4){0.f, 0.f, 0.f, 0.f};
      if (g + 1 < ge) {
        if (bh2 != bh) {
          w_h = expf(s_v[bh2 % 12]) + 1.0f;
          lr_h = log2f(expf(s_r[bh2 % 12]) + 1.0f);
        }
        const unsigned short* Qp2 = qb + (size_t)bh2 * 131072;
        const int qbase2 = qt2 * 64;
#pragma unroll
        for (int n = 0; n < 2; ++n)
#pragma unroll
          for (int kc = 0; kc < 2; ++kc)
            qf[n][kc] = *(const short8*)(Qp2 + (size_t)(qbase2 + wn * 32 + n * 16 + l15) * 64 +
                                         kc * 32 + l4 * 8);
      }
    }
    bh = bh2; qt = qt2; kt = kt2;
  }
}

// ---------------------------------------------------------------------------
// Kernel 2b: sum <=3 partials per row + TanhNorm -> attn bf16 [B,T,768].
// 4 threads per (bh,t) row, 16 d each. grid = 768; block = 256.
// ---------------------------------------------------------------------------
__global__ __launch_bounds__(256) void k_tanh(const float* __restrict__ partials,
                                              unsigned short* __restrict__ attn) {
  const int tid = threadIdx.x;
  const int rg = blockIdx.x * 64 + (tid >> 2);  // 0..49151 = bh*2048 + t
  const int q4 = tid & 3;
  const int bh = rg >> 11, t = rg & 2047;
  const int qt = t >> 6;
  const int g0 = bh * 528 + qt * (qt + 1) / 2;
  const int cnt = strip_of(g0 + qt) - strip_of(g0) + 1;  // strips covering row
  float v[16];
  const float* b0 = partials + ((size_t)bh * 2048 + t) * 64 + q4 * 16;
#pragma unroll
  for (int c = 0; c < 4; ++c) {
    float4v f = *(const float4v*)(b0 + c * 4);
    v[c * 4 + 0] = f.x; v[c * 4 + 1] = f.y; v[c * 4 + 2] = f.z; v[c * 4 + 3] = f.w;
  }
  for (int p = 1; p < cnt; ++p) {
    const float* bp = b0 + (size_t)p * 3145728;  // 24*2048*64
#pragma unroll
    for (int c = 0; c < 4; ++c) {
      float4v f = *(const float4v*)(bp + c * 4);
      v[c * 4 + 0] += f.x; v[c * 4 + 1] += f.y; v[c * 4 + 2] += f.z; v[c * 4 + 3] += f.w;
    }
  }
  float ss = 0.f;
#pragma unroll
  for (int j = 0; j < 16; ++j) ss += v[j] * v[j];
  ss += __shfl_xor(ss, 1);
  ss += __shfl_xor(ss, 2);
  const float nrm = sqrtf(ss);
  const float sc = tanhf(nrm) / (nrm + 1e-8f);
  unsigned short* dst =
      attn + ((size_t)((bh / 12) * 2048 + t)) * 768 + (bh % 12) * 64 + q4 * 16;
  uint4v o0 = {pack2(v[0] * sc, v[1] * sc), pack2(v[2] * sc, v[3] * sc),
               pack2(v[4] * sc, v[5] * sc), pack2(v[6] * sc, v[7] * sc)};
  uint4v o1 = {pack2(v[8] * sc, v[9] * sc), pack2(v[10] * sc, v[11] * sc),
               pack2(v[12] * sc, v[13] * sc), pack2(v[14] * sc, v[15] * sc)};
  *(uint4v*)(dst) = o0;
  *(uint4v*)(dst + 8) = o1;
}

// ---------------------------------------------------------------------------
// Kernel 3: out = attn[4096x768](bf16) @ Wo^T(bf16) -> f32. 128x128 tile,
// DOUBLE-BUFFERED K-loop (round-9 proven, unchanged). grid (32,6); block 256.
// ---------------------------------------------------------------------------
__global__ __launch_bounds__(256) void k_outproj(const unsigned short* __restrict__ attn,
                                                 const unsigned short* __restrict__ Wob,
                                                 float* __restrict__ out) {
  __shared__ alignas(16) unsigned char smem[65536];
  const int mbase = blockIdx.x * 128;
  const int nb = blockIdx.y;
  const int tid = threadIdx.x;
  const int lane = tid & 63;
  const int wv = tid >> 6;
  const int wm = wv >> 1, wn = wv & 1;
  const int l15 = lane & 15, l4 = lane >> 4;
  const int srow8 = lane >> 3;
  const int schunk = (lane & 7) ^ srow8;

  f32x4 acc[4][4];
#pragma unroll
  for (int m = 0; m < 4; ++m)
#pragma unroll
    for (int n = 0; n < 4; ++n) acc[m][n] = (f32x4){0.f, 0.f, 0.f, 0.f};

#pragma unroll
  for (int i = 0; i < 4; ++i) {
    const int j = wv * 4 + i;
    gload_lds16(attn + (size_t)(mbase + j * 8 + srow8) * 768 + schunk * 8, smem + j * 1024);
    gload_lds16(Wob + (size_t)(nb * 128 + j * 8 + srow8) * 768 + schunk * 8,
                smem + 16384 + j * 1024);
  }

  for (int ks = 0; ks < 12; ++ks) {
    const int cur = (ks & 1) * 32768;
    asm volatile("s_waitcnt vmcnt(0)" ::: "memory");
    __builtin_amdgcn_sched_barrier(0);
    __builtin_amdgcn_s_barrier();
    __builtin_amdgcn_sched_barrier(0);
    if (ks < 11) {
      const int nxt = ((ks + 1) & 1) * 32768;
      const int k0n = (ks + 1) * 64;
#pragma unroll
      for (int i = 0; i < 4; ++i) {
        const int j = wv * 4 + i;
        gload_lds16(attn + (size_t)(mbase + j * 8 + srow8) * 768 + k0n + schunk * 8,
                    smem + nxt + j * 1024);
        gload_lds16(Wob + (size_t)(nb * 128 + j * 8 + srow8) * 768 + k0n + schunk * 8,
                    smem + nxt + 16384 + j * 1024);
      }
      __builtin_amdgcn_sched_barrier(0);
    }
    __builtin_amdgcn_s_setprio(1);
#pragma unroll
    for (int kc = 0; kc < 2; ++kc) {
      const int cx = (kc << 2) | l4;
      short8 ar[4], br[4];
#pragma unroll
      for (int m = 0; m < 4; ++m) {
        const int r = wm * 64 + m * 16 + l15;
        ar[m] = *(const short8*)(smem + cur + r * 128 + ((cx ^ (r & 7)) << 4));
      }
#pragma unroll
      for (int n = 0; n < 4; ++n) {
        const int r = wn * 64 + n * 16 + l15;
        br[n] = *(const short8*)(smem + cur + 16384 + r * 128 + ((cx ^ (r & 7)) << 4));
      }
#pragma unroll
      for (int m = 0; m < 4; ++m)
#pragma unroll
        for (int n = 0; n < 4; ++n) acc[m][n] = MFMA_BF16(ar[m], br[n], acc[m][n]);
    }
    __builtin_amdgcn_s_setprio(0);
  }
#pragma unroll
  for (int m = 0; m < 4; ++m)
#pragma unroll
    for (int n = 0; n < 4; ++n)
#pragma unroll
      for (int j = 0; j < 4; ++j)
        out[(size_t)(mbase + wm * 64 + m * 16 + l4 * 4 + j) * 768 + nb * 128 + wn * 64 + n * 16 +
            l15] = acc[m][n][j];
}

extern "C" void kernel_launch(void* const* d_in, const int* in_sizes, int n_in, void* d_out,
                              int out_size, void* d_ws, size_t ws_size, hipStream_t stream) {
  (void)in_sizes;
  (void)n_in;
  (void)out_size;
  (void)ws_size;
  const float* query = (const float*)d_in[0];
  const float* key = (const float*)d_in[1];
  const float* value = (const float*)d_in[2];
  const float* Wq = (const float*)d_in[3];
  const float* Wk = (const float*)d_in[4];
  const float* Wv = (const float*)d_in[5];
  const float* Wo = (const float*)d_in[6];
  const float* s_v = (const float*)d_in[7];
  const float* s_r = (const float*)d_in[8];
  float* out = (float*)d_out;

  // ws layout (bf16 elems): [Xb 3x3145728 | Wb 4x589824 | qb | kb | vtb |
  // partials f32 3x24x2048x64]. attn aliases Xb (dead after k_proj). ~80 MB.
  unsigned short* cvt = (unsigned short*)d_ws;
  unsigned short* Xb = cvt;
  unsigned short* Wb = cvt + 9437184;
  unsigned short* qb = cvt + 11796480;
  unsigned short* kb = qb + 3145728;
  unsigned short* vtb = kb + 3145728;
  float* partials = (float*)(cvt + 21233664);
  unsigned short* attn = cvt;

  k_cvt<<<5760, 256, 0, stream>>>(query, key, value, Wq, Wk, Wv, Wo, cvt);
  k_proj<<<dim3(32, 6, 3), 256, 0, stream>>>(Xb, Wb, qb, kb, vtb);
  k_attn<<<dim3(768), 256, 0, stream>>>(qb, kb, vtb, s_v, s_r, partials);
  k_tanh<<<dim3(768), 256, 0, stream>>>(partials, attn);
  k_outproj<<<dim3(32, 6), 256, 0, stream>>>(attn, Wb + 3 * 589824, out);
}

// Round 14
// 88.988 us; speedup vs baseline: 1.1622x; 1.1622x over previous
//
#include <hip/hip_runtime.h>
#include <hip/hip_bf16.h>
#include <math.h>

// ScreeningAttention: B=2, T=2048, D_MODEL=768, H=12, D=64
// Round 14 = round-11 artifact (89.5us best) + k_outproj retiled 128x64
// (grid 384, LDS 48KB, up to 3 blocks/CU vs 192 blocks @ 0.75/CU).
// k_cvt (f32->bf16 once) -> k_proj (128x128 dbuf GEMM + l2norm, V transposed)
// -> k_attn (balanced causal screening attn, dbuf prefetch) -> k_outproj.
// LESSONS: v_cvt_pk_bf16_f32 asm pack = correctness bug (r4/6/7). A-direct /
// fused-cvt k_proj = regression (r10 uncoalesced, r12 serial path). k_attn
// strip-tiling = regression (r13: L2 locality loss, FETCH 13->79MB).

typedef __attribute__((ext_vector_type(8))) short short8;     // 8 bf16, MFMA A/B frag
typedef __attribute__((ext_vector_type(4))) float f32x4;      // MFMA C/D frag
typedef __attribute__((ext_vector_type(4))) unsigned int uint4v;
typedef __attribute__((ext_vector_type(2))) unsigned int uint2v;
typedef __attribute__((ext_vector_type(4))) float float4v;

#define MFMA_BF16(a, b, c) __builtin_amdgcn_mfma_f32_16x16x32_bf16((a), (b), (c), 0, 0, 0)

// round-to-nearest-even f32->bf16, bit-manip (round-3-proven).
static __device__ __forceinline__ unsigned short f2bf(float f) {
  union { float f; unsigned u; } v; v.f = f;
  unsigned r = v.u + 0x7FFFu + ((v.u >> 16) & 1u);
  return (unsigned short)(r >> 16);
}
static __device__ __forceinline__ unsigned pack2(float a, float b) {
  return (unsigned)f2bf(a) | ((unsigned)f2bf(b) << 16);
}
// async global->LDS, 16B per lane. LDS dest = wave-uniform base + lane*16.
static __device__ __forceinline__ void gload_lds16(const void* g, void* l) {
  __builtin_amdgcn_global_load_lds((const __attribute__((address_space(1))) unsigned int*)g,
                                   (__attribute__((address_space(3))) unsigned int*)l, 16, 0, 0);
}

// ---------------------------------------------------------------------------
// Kernel 0: convert Xq,Xk,Xv (3x3145728) + Wq,Wk,Wv,Wo (4x589824) f32->bf16
// into one contiguous bf16 region. grid 5760x256, 8 elems/thread.
// ---------------------------------------------------------------------------
__global__ __launch_bounds__(256) void k_cvt(
    const float* __restrict__ s0, const float* __restrict__ s1, const float* __restrict__ s2,
    const float* __restrict__ s3, const float* __restrict__ s4, const float* __restrict__ s5,
    const float* __restrict__ s6, unsigned short* __restrict__ dst) {
  const size_t e = ((size_t)blockIdx.x * 256 + threadIdx.x) * 8;
  const float* src;
  size_t off;
  if (e < 9437184) {
    const int i = (int)(e / 3145728);
    src = (i == 0) ? s0 : (i == 1) ? s1 : s2;
    off = e - (size_t)i * 3145728;
  } else {
    const size_t ew = e - 9437184;
    const int i = (int)(ew / 589824);
    src = (i == 0) ? s3 : (i == 1) ? s4 : (i == 2) ? s5 : s6;
    off = ew - (size_t)i * 589824;
  }
  const float4v f0 = *(const float4v*)(src + off);
  const float4v f1 = *(const float4v*)(src + off + 4);
  uint4v u = {pack2(f0.x, f0.y), pack2(f0.z, f0.w), pack2(f1.x, f1.y), pack2(f1.z, f1.w)};
  *(uint4v*)(dst + e) = u;
}

// ---------------------------------------------------------------------------
// Kernel 1: QKV projection (bf16 inputs) + per-head l2 normalization.
// 128x128 tile, BK=64, 4 waves (2x2, 64x64 each, 4x4 frags).
// K-loop DOUBLE-BUFFERED (A0/B0 @0/16K, A1/B1 @32K/48K): per iter
// {vmcnt(0)+barrier -> prefetch ks+1 -> MFMA from cur}. One barrier/k-step.
// LDS tiles linear with XOR chunk-swizzle (chunk ^= row&7) on both sides.
// which==2 (V) writes TRANSPOSED to vtb [bh][d][t].
// grid = (32, 6, 3); block = 256.
// ---------------------------------------------------------------------------
__global__ __launch_bounds__(256) void k_proj(
    const unsigned short* __restrict__ Xb, const unsigned short* __restrict__ Wb,
    unsigned short* __restrict__ qb, unsigned short* __restrict__ kb,
    unsigned short* __restrict__ vtb) {
  __shared__ alignas(16) unsigned char smem[65536];
  float* o_s = (float*)smem;               // f32[128][68] epilogue alias (34816 B)
  unsigned short* vt_s = (unsigned short*)smem;  // bf16[64][136] V epilogue alias

  const int which = blockIdx.z;
  const unsigned short* X = Xb + (size_t)which * 3145728;
  const unsigned short* W = Wb + (size_t)which * 589824;

  const int mbase = blockIdx.x * 128;
  const int nb = blockIdx.y;  // 2 heads per block
  const int tid = threadIdx.x;
  const int lane = tid & 63;
  const int wv = tid >> 6;
  const int wm = wv >> 1, wn = wv & 1;
  const int l15 = lane & 15, l4 = lane >> 4;

  const int srow8 = lane >> 3;
  const int schunk = (lane & 7) ^ srow8;

  f32x4 acc[4][4];
#pragma unroll
  for (int m = 0; m < 4; ++m)
#pragma unroll
    for (int n = 0; n < 4; ++n) acc[m][n] = (f32x4){0.f, 0.f, 0.f, 0.f};

  // prologue: stage ks=0 into buffer 0 (loop-top vmcnt+barrier covers the wait)
#pragma unroll
  for (int i = 0; i < 4; ++i) {
    const int j = wv * 4 + i;
    gload_lds16(X + (size_t)(mbase + j * 8 + srow8) * 768 + schunk * 8, smem + j * 1024);
    gload_lds16(W + (size_t)(nb * 128 + j * 8 + srow8) * 768 + schunk * 8,
                smem + 16384 + j * 1024);
  }

  for (int ks = 0; ks < 12; ++ks) {
    const int cur = (ks & 1) * 32768;
    // my prefetch done -> barrier -> everyone's prefetch done
    asm volatile("s_waitcnt vmcnt(0)" ::: "memory");
    __builtin_amdgcn_sched_barrier(0);
    __builtin_amdgcn_s_barrier();
    __builtin_amdgcn_sched_barrier(0);
    if (ks < 11) {
      const int nxt = ((ks + 1) & 1) * 32768;
      const int k0n = (ks + 1) * 64;
#pragma unroll
      for (int i = 0; i < 4; ++i) {
        const int j = wv * 4 + i;
        gload_lds16(X + (size_t)(mbase + j * 8 + srow8) * 768 + k0n + schunk * 8,
                    smem + nxt + j * 1024);
        gload_lds16(W + (size_t)(nb * 128 + j * 8 + srow8) * 768 + k0n + schunk * 8,
                    smem + nxt + 16384 + j * 1024);
      }
      __builtin_amdgcn_sched_barrier(0);  // pin prefetch issue before compute
    }
    __builtin_amdgcn_s_setprio(1);
#pragma unroll
    for (int kc = 0; kc < 2; ++kc) {
      const int cx = (kc << 2) | l4;
      short8 ar[4], br[4];
#pragma unroll
      for (int m = 0; m < 4; ++m) {
        const int r = wm * 64 + m * 16 + l15;
        ar[m] = *(const short8*)(smem + cur + r * 128 + ((cx ^ (r & 7)) << 4));
      }
#pragma unroll
      for (int n = 0; n < 4; ++n) {
        const int r = wn * 64 + n * 16 + l15;
        br[n] = *(const short8*)(smem + cur + 16384 + r * 128 + ((cx ^ (r & 7)) << 4));
      }
#pragma unroll
      for (int m = 0; m < 4; ++m)
#pragma unroll
        for (int n = 0; n < 4; ++n) acc[m][n] = MFMA_BF16(ar[m], br[n], acc[m][n]);
    }
    __builtin_amdgcn_s_setprio(0);
  }

  // epilogue: per col-half pass p (head h = nb*2+p)
  const int b = mbase >> 11;
  const int tbase = mbase & 2047;
  const int row2 = tid >> 1, half = tid & 1;
  for (int p = 0; p < 2; ++p) {
    __syncthreads();
    if (wn == p) {
#pragma unroll
      for (int m = 0; m < 4; ++m)
#pragma unroll
        for (int n = 0; n < 4; ++n)
#pragma unroll
          for (int j = 0; j < 4; ++j)
            o_s[(wm * 64 + m * 16 + l4 * 4 + j) * 68 + n * 16 + l15] = acc[m][n][j];
    }
    __syncthreads();
    float v[32];
    float ss = 0.f;
#pragma unroll
    for (int c = 0; c < 8; ++c) {
      float4v f = *(const float4v*)(o_s + row2 * 68 + half * 32 + c * 4);
      v[c * 4 + 0] = f.x; v[c * 4 + 1] = f.y; v[c * 4 + 2] = f.z; v[c * 4 + 3] = f.w;
      ss += f.x * f.x + f.y * f.y + f.z * f.z + f.w * f.w;
    }
    ss += __shfl_xor(ss, 1);
    const float inv = 1.f / fmaxf(sqrtf(ss), 1e-8f);
    const int h = nb * 2 + p, bh = b * 12 + h;
    if (which < 2) {
      unsigned short* outp =
          ((which == 0) ? qb : kb) + ((size_t)bh * 2048 + tbase + row2) * 64 + half * 32;
#pragma unroll
      for (int c = 0; c < 4; ++c) {
        uint4v o = {pack2(v[c * 8 + 0] * inv, v[c * 8 + 1] * inv),
                    pack2(v[c * 8 + 2] * inv, v[c * 8 + 3] * inv),
                    pack2(v[c * 8 + 4] * inv, v[c * 8 + 5] * inv),
                    pack2(v[c * 8 + 6] * inv, v[c * 8 + 7] * inv)};
        *(uint4v*)(outp + c * 8) = o;
      }
      __syncthreads();
    } else {
      __syncthreads();  // o_s reads done; vt_s aliases o_s
#pragma unroll
      for (int c = 0; c < 32; ++c)
        vt_s[(half * 32 + c) * 136 + row2] = f2bf(v[c] * inv);
      __syncthreads();
      const int d = tid >> 2, tc = (tid & 3) * 32;
      unsigned short* dst = vtb + ((size_t)bh * 64 + d) * 2048 + tbase + tc;
#pragma unroll
      for (int c = 0; c < 4; ++c)
        *(uint4v*)(dst + c * 8) = *(const uint4v*)(vt_s + d * 136 + tc + c * 8);
      __syncthreads();
    }
  }
}

// ---------------------------------------------------------------------------
// Kernel 2: causal screening attention (ROUND-11 PASSING, unchanged).
// Swapped-S MFMA (reg-dim = keys), Q fragments read directly from global,
// K/V^T DOUBLE-BUFFERED via global_load_lds; full vmcnt(0) drains only.
// Balanced flat grid (heavy+light task pairing).
// LDS: K0 @0, K1 @8192, V0 @16384, V1 @24576, p_s @32768 (9216). 41984 B.
// block = 256 (4 waves, 2x2).
// ---------------------------------------------------------------------------
__global__ __launch_bounds__(256) void k_attn(
    const unsigned short* __restrict__ qb, const unsigned short* __restrict__ kb,
    const unsigned short* __restrict__ vtb, const float* __restrict__ s_v,
    const float* __restrict__ s_r, unsigned short* __restrict__ attn) {
  __shared__ alignas(16) unsigned char smem[41984];
  unsigned short* p_s = (unsigned short*)(smem + 32768);  // [64 q][72 key] bf16
  float* o_s = (float*)smem;                              // [64][68] f32 epilogue alias

  const int bid = blockIdx.x;
  const int ii = bid & 255, jj = bid >> 8;
  const int rank = (jj == 0) ? ii : (jj == 1) ? (511 - ii) : (512 + ii);
  const int qt = 31 - (rank / 24);  // heavy tasks at low rank
  const int bh = rank % 24;
  const int b = bh / 12, h = bh % 12;
  const int qbase = qt * 64;
  const unsigned short* Qp = qb + (size_t)bh * 2048 * 64;
  const unsigned short* Kp = kb + (size_t)bh * 2048 * 64;
  const unsigned short* VTp = vtb + (size_t)bh * 64 * 2048;

  const int tid = threadIdx.x;
  const int lane = tid & 63;
  const int wv = tid >> 6;
  const int wm = wv >> 1, wn = wv & 1;  // S: wm=keys, wn=q. PV: wm=d, wn=q.
  const int l15 = lane & 15, l4 = lane >> 4;
  const int srow8 = lane >> 3;
  const int schunk = (lane & 7) ^ srow8;

  const float w_h = expf(s_v[h]) + 1.0f;          // decay exponent, [2,256]
  const float lr_h = log2f(expf(s_r[h]) + 1.0f);  // log2 of per-head scale

  // prologue: issue kt=0 K/V gloads (loop-top vmcnt(0)+barrier covers them)
#pragma unroll
  for (int i = 0; i < 2; ++i) {
    const int j = wv * 2 + i;
    gload_lds16(Kp + (size_t)(j * 8 + srow8) * 64 + schunk * 8, smem + j * 1024);
    gload_lds16(VTp + (size_t)(j * 8 + srow8) * 2048 + schunk * 8, smem + 16384 + j * 1024);
  }

  // hoist Q fragments (B-operand of swapped S) straight from global (r3-proven)
  short8 qf[2][2];
#pragma unroll
  for (int n = 0; n < 2; ++n)
#pragma unroll
    for (int kc = 0; kc < 2; ++kc)
      qf[n][kc] = *(const short8*)(Qp + (size_t)(qbase + wn * 32 + n * 16 + l15) * 64 + kc * 32 +
                                   l4 * 8);

  f32x4 acc_o[2][2];  // [qi][di]
#pragma unroll
  for (int m = 0; m < 2; ++m)
#pragma unroll
    for (int n = 0; n < 2; ++n) acc_o[m][n] = (f32x4){0.f, 0.f, 0.f, 0.f};

  for (int kt = 0; kt <= qt; ++kt) {
    const int cur = (kt & 1) * 8192;
    // wait current tile's K/V (the only outstanding VMEM = prev prefetch), sync
    asm volatile("s_waitcnt vmcnt(0)" ::: "memory");
    __builtin_amdgcn_sched_barrier(0);
    __builtin_amdgcn_s_barrier();
    __builtin_amdgcn_sched_barrier(0);
    // prefetch kt+1 into the other buffer (all waves past kt-1 reads now)
    if (kt < qt) {
      const int nxt = ((kt + 1) & 1) * 8192;
      const int kb2 = (kt + 1) * 64;
#pragma unroll
      for (int i = 0; i < 2; ++i) {
        const int j = wv * 2 + i;
        gload_lds16(Kp + (size_t)(kb2 + j * 8 + srow8) * 64 + schunk * 8, smem + nxt + j * 1024);
        gload_lds16(VTp + (size_t)(j * 8 + srow8) * 2048 + kb2 + schunk * 8,
                    smem + 16384 + nxt + j * 1024);
      }
      __builtin_amdgcn_sched_barrier(0);  // pin prefetch issue before compute
    }
    // S^T = K Q^T : rows = keys, cols = q
    f32x4 s_acc[2][2];
#pragma unroll
    for (int m = 0; m < 2; ++m)
#pragma unroll
      for (int n = 0; n < 2; ++n) s_acc[m][n] = (f32x4){0.f, 0.f, 0.f, 0.f};
    __builtin_amdgcn_s_setprio(1);
#pragma unroll
    for (int kc = 0; kc < 2; ++kc) {
      const int cx = (kc << 2) | l4;
      const int r0 = wm * 32 + l15, r1 = wm * 32 + 16 + l15;
      short8 a0 = *(const short8*)(smem + cur + r0 * 128 + ((cx ^ (r0 & 7)) << 4));
      short8 a1 = *(const short8*)(smem + cur + r1 * 128 + ((cx ^ (r1 & 7)) << 4));
      s_acc[0][0] = MFMA_BF16(a0, qf[0][kc], s_acc[0][0]);
      s_acc[0][1] = MFMA_BF16(a0, qf[1][kc], s_acc[0][1]);
      s_acc[1][0] = MFMA_BF16(a1, qf[0][kc], s_acc[1][0]);
      s_acc[1][1] = MFMA_BF16(a1, qf[1][kc], s_acc[1][1]);
    }
    __builtin_amdgcn_s_setprio(0);
    // alpha = r * clamp((s+1)/2)^w ; frag reg-dim = consecutive keys -> b64 stores
    const bool diag = (kt == qt);
#pragma unroll
    for (int m = 0; m < 2; ++m)
#pragma unroll
      for (int n = 0; n < 2; ++n) {
        const int lkb = wm * 32 + m * 16 + l4 * 4;  // key base (reg dim)
        const int lq = wn * 32 + n * 16 + l15;      // q (lane dim)
        float av[4];
#pragma unroll
        for (int t = 0; t < 4; ++t) {
          const float base = __builtin_amdgcn_fmed3f(fmaf(s_acc[m][n][t], 0.5f, 0.5f), 0.f, 1.f);
          float a = __builtin_amdgcn_exp2f(fmaf(w_h, __builtin_amdgcn_logf(base), lr_h));
          if (diag && (lkb + t) > lq) a = 0.f;
          av[t] = a;
        }
        uint2v u = {pack2(av[0], av[1]), pack2(av[2], av[3])};
        *(uint2v*)(p_s + lq * 72 + lkb) = u;
      }
    // drain LDS writes of P, then sync (raw barrier: keep prefetch in flight)
    asm volatile("s_waitcnt lgkmcnt(0)" ::: "memory");
    __builtin_amdgcn_sched_barrier(0);
    __builtin_amdgcn_s_barrier();
    __builtin_amdgcn_sched_barrier(0);
    // O += P V : A = P[q][key] (padded b128 rows), B = V^T[d][key] (swizzled)
    __builtin_amdgcn_s_setprio(1);
#pragma unroll
    for (int kc = 0; kc < 2; ++kc) {
      const int cx = (kc << 2) | l4;
      const int r0 = wm * 32 + l15, r1 = wm * 32 + 16 + l15;
      short8 pa0 = *(const short8*)(p_s + (wn * 32 + l15) * 72 + kc * 32 + l4 * 8);
      short8 pa1 = *(const short8*)(p_s + (wn * 32 + 16 + l15) * 72 + kc * 32 + l4 * 8);
      short8 vb0 = *(const short8*)(smem + 16384 + cur + r0 * 128 + ((cx ^ (r0 & 7)) << 4));
      short8 vb1 = *(const short8*)(smem + 16384 + cur + r1 * 128 + ((cx ^ (r1 & 7)) << 4));
      acc_o[0][0] = MFMA_BF16(pa0, vb0, acc_o[0][0]);
      acc_o[0][1] = MFMA_BF16(pa0, vb1, acc_o[0][1]);
      acc_o[1][0] = MFMA_BF16(pa1, vb0, acc_o[1][0]);
      acc_o[1][1] = MFMA_BF16(pa1, vb1, acc_o[1][1]);
    }
    __builtin_amdgcn_s_setprio(0);
  }
  __syncthreads();
#pragma unroll
  for (int qi = 0; qi < 2; ++qi)
#pragma unroll
    for (int di = 0; di < 2; ++di)
#pragma unroll
      for (int j = 0; j < 4; ++j)
        o_s[(wn * 32 + qi * 16 + l4 * 4 + j) * 68 + wm * 32 + di * 16 + l15] = acc_o[qi][di][j];
  __syncthreads();
  // TanhNorm: out = tanh(n) * out / (n + eps)
  {
    const int row = tid >> 2, q4 = tid & 3;
    float vals[16];
    float ss = 0.f;
#pragma unroll
    for (int j = 0; j < 16; ++j) {
      vals[j] = o_s[row * 68 + q4 * 16 + j];
      ss += vals[j] * vals[j];
    }
    ss += __shfl_xor(ss, 1);
    ss += __shfl_xor(ss, 2);
    const float nrm = sqrtf(ss);
    const float sc = tanhf(nrm) / (nrm + 1e-8f);
    unsigned short* dst = attn + (size_t)(b * 2048 + qbase + row) * 768 + h * 64 + q4 * 16;
    uint4v o0 = {pack2(vals[0] * sc, vals[1] * sc), pack2(vals[2] * sc, vals[3] * sc),
                 pack2(vals[4] * sc, vals[5] * sc), pack2(vals[6] * sc, vals[7] * sc)};
    uint4v o1 = {pack2(vals[8] * sc, vals[9] * sc), pack2(vals[10] * sc, vals[11] * sc),
                 pack2(vals[12] * sc, vals[13] * sc), pack2(vals[14] * sc, vals[15] * sc)};
    *(uint4v*)(dst) = o0;
    *(uint4v*)(dst + 8) = o1;
  }
}

// ---------------------------------------------------------------------------
// Kernel 3: out = attn[4096x768](bf16) @ Wo^T(bf16) -> f32. 128x64 tile
// (retiled from 128x128: grid 384 covers all 256 CUs; LDS 48KB -> 3 blk/CU).
// Same proven dbuf schedule. A frags 4, B frags 2, acc[4][2].
// LDS: A0@0 (16K), B0@16384 (8K), A1@24576, B1@40960. grid (32,12); block 256.
// ---------------------------------------------------------------------------
__global__ __launch_bounds__(256) void k_outproj(const unsigned short* __restrict__ attn,
                                                 const unsigned short* __restrict__ Wob,
                                                 float* __restrict__ out) {
  __shared__ alignas(16) unsigned char smem[49152];
  const int mbase = blockIdx.x * 128;
  const int nbase = blockIdx.y * 64;
  const int tid = threadIdx.x;
  const int lane = tid & 63;
  const int wv = tid >> 6;
  const int wm = wv >> 1, wn = wv & 1;
  const int l15 = lane & 15, l4 = lane >> 4;
  const int srow8 = lane >> 3;
  const int schunk = (lane & 7) ^ srow8;

  f32x4 acc[4][2];
#pragma unroll
  for (int m = 0; m < 4; ++m)
#pragma unroll
    for (int n = 0; n < 2; ++n) acc[m][n] = (f32x4){0.f, 0.f, 0.f, 0.f};

  // prologue: stage ks=0 into buffer 0 (A: 4 instrs/wave, B: 2 instrs/wave)
#pragma unroll
  for (int i = 0; i < 4; ++i) {
    const int j = wv * 4 + i;
    gload_lds16(attn + (size_t)(mbase + j * 8 + srow8) * 768 + schunk * 8, smem + j * 1024);
  }
#pragma unroll
  for (int i = 0; i < 2; ++i) {
    const int j = wv * 2 + i;
    gload_lds16(Wob + (size_t)(nbase + j * 8 + srow8) * 768 + schunk * 8,
                smem + 16384 + j * 1024);
  }

  for (int ks = 0; ks < 12; ++ks) {
    const int cur = (ks & 1) * 24576;
    asm volatile("s_waitcnt vmcnt(0)" ::: "memory");
    __builtin_amdgcn_sched_barrier(0);
    __builtin_amdgcn_s_barrier();
    __builtin_amdgcn_sched_barrier(0);
    if (ks < 11) {
      const int nxt = ((ks + 1) & 1) * 24576;
      const int k0n = (ks + 1) * 64;
#pragma unroll
      for (int i = 0; i < 4; ++i) {
        const int j = wv * 4 + i;
        gload_lds16(attn + (size_t)(mbase + j * 8 + srow8) * 768 + k0n + schunk * 8,
                    smem + nxt + j * 1024);
      }
#pragma unroll
      for (int i = 0; i < 2; ++i) {
        const int j = wv * 2 + i;
        gload_lds16(Wob + (size_t)(nbase + j * 8 + srow8) * 768 + k0n + schunk * 8,
                    smem + nxt + 16384 + j * 1024);
      }
      __builtin_amdgcn_sched_barrier(0);
    }
    __builtin_amdgcn_s_setprio(1);
#pragma unroll
    for (int kc = 0; kc < 2; ++kc) {
      const int cx = (kc << 2) | l4;
      short8 ar[4], br[2];
#pragma unroll
      for (int m = 0; m < 4; ++m) {
        const int r = wm * 64 + m * 16 + l15;
        ar[m] = *(const short8*)(smem + cur + r * 128 + ((cx ^ (r & 7)) << 4));
      }
#pragma unroll
      for (int n = 0; n < 2; ++n) {
        const int r = wn * 32 + n * 16 + l15;
        br[n] = *(const short8*)(smem + cur + 16384 + r * 128 + ((cx ^ (r & 7)) << 4));
      }
#pragma unroll
      for (int m = 0; m < 4; ++m)
#pragma unroll
        for (int n = 0; n < 2; ++n) acc[m][n] = MFMA_BF16(ar[m], br[n], acc[m][n]);
    }
    __builtin_amdgcn_s_setprio(0);
  }
#pragma unroll
  for (int m = 0; m < 4; ++m)
#pragma unroll
    for (int n = 0; n < 2; ++n)
#pragma unroll
      for (int j = 0; j < 4; ++j)
        out[(size_t)(mbase + wm * 64 + m * 16 + l4 * 4 + j) * 768 + nbase + wn * 32 + n * 16 +
            l15] = acc[m][n][j];
}

extern "C" void kernel_launch(void* const* d_in, const int* in_sizes, int n_in, void* d_out,
                              int out_size, void* d_ws, size_t ws_size, hipStream_t stream) {
  (void)in_sizes;
  (void)n_in;
  (void)out_size;
  (void)ws_size;
  const float* query = (const float*)d_in[0];
  const float* key = (const float*)d_in[1];
  const float* value = (const float*)d_in[2];
  const float* Wq = (const float*)d_in[3];
  const float* Wk = (const float*)d_in[4];
  const float* Wv = (const float*)d_in[5];
  const float* Wo = (const float*)d_in[6];
  const float* s_v = (const float*)d_in[7];
  const float* s_r = (const float*)d_in[8];
  float* out = (float*)d_out;

  // ws layout (bf16 elems): [Xb 3x3145728 | Wb 4x589824 | qb | kb | vtb]
  // attn aliases Xb (dead after k_proj). Total 42.5 MB.
  unsigned short* cvt = (unsigned short*)d_ws;
  unsigned short* Xb = cvt;
  unsigned short* Wb = cvt + 9437184;
  unsigned short* qb = cvt + 11796480;
  unsigned short* kb = qb + 3145728;
  unsigned short* vtb = kb + 3145728;
  unsigned short* attn = cvt;

  k_cvt<<<5760, 256, 0, stream>>>(query, key, value, Wq, Wk, Wv, Wo, cvt);
  k_proj<<<dim3(32, 6, 3), 256, 0, stream>>>(Xb, Wb, qb, kb, vtb);
  k_attn<<<dim3(768), 256, 0, stream>>>(qb, kb, vtb, s_v, s_r, attn);
  k_outproj<<<dim3(32, 12), 256, 0, stream>>>(attn, Wb + 3 * 589824, out);
}

// Round 15
// 82.629 us; speedup vs baseline: 1.2516x; 1.0770x over previous
//
#include <hip/hip_runtime.h>
#include <hip/hip_bf16.h>
#include <math.h>

// ScreeningAttention: B=2, T=2048, D_MODEL=768, H=12, D=64
// Round 15 = round-14 (89.0us best) + k_proj retiled 128x64 (1 head/block):
// grid (32,12,3)=1152 blocks, LDS 48KB -> 3 blocks/CU + backfill queue
// (was 128x128, 64KB, 2/CU, no backfill). Same proven dbuf schedule; compute
// structure identical to r14's k_outproj (ar[4], br[2], acc[4][2]).
// k_cvt -> k_proj -> k_attn -> k_outproj (128x64, r14-proven).
// LESSONS: v_cvt_pk_bf16_f32 asm pack = correctness bug (r4/6/7). A-direct /
// fused-cvt k_proj = regression (r10 uncoalesced, r12 serial path). k_attn
// strip-tiling = regression (r13: L2 locality loss, FETCH 13->79MB).

typedef __attribute__((ext_vector_type(8))) short short8;     // 8 bf16, MFMA A/B frag
typedef __attribute__((ext_vector_type(4))) float f32x4;      // MFMA C/D frag
typedef __attribute__((ext_vector_type(4))) unsigned int uint4v;
typedef __attribute__((ext_vector_type(2))) unsigned int uint2v;
typedef __attribute__((ext_vector_type(4))) float float4v;

#define MFMA_BF16(a, b, c) __builtin_amdgcn_mfma_f32_16x16x32_bf16((a), (b), (c), 0, 0, 0)

// round-to-nearest-even f32->bf16, bit-manip (round-3-proven).
static __device__ __forceinline__ unsigned short f2bf(float f) {
  union { float f; unsigned u; } v; v.f = f;
  unsigned r = v.u + 0x7FFFu + ((v.u >> 16) & 1u);
  return (unsigned short)(r >> 16);
}
static __device__ __forceinline__ unsigned pack2(float a, float b) {
  return (unsigned)f2bf(a) | ((unsigned)f2bf(b) << 16);
}
// async global->LDS, 16B per lane. LDS dest = wave-uniform base + lane*16.
static __device__ __forceinline__ void gload_lds16(const void* g, void* l) {
  __builtin_amdgcn_global_load_lds((const __attribute__((address_space(1))) unsigned int*)g,
                                   (__attribute__((address_space(3))) unsigned int*)l, 16, 0, 0);
}

// ---------------------------------------------------------------------------
// Kernel 0: convert Xq,Xk,Xv (3x3145728) + Wq,Wk,Wv,Wo (4x589824) f32->bf16
// into one contiguous bf16 region. grid 5760x256, 8 elems/thread.
// ---------------------------------------------------------------------------
__global__ __launch_bounds__(256) void k_cvt(
    const float* __restrict__ s0, const float* __restrict__ s1, const float* __restrict__ s2,
    const float* __restrict__ s3, const float* __restrict__ s4, const float* __restrict__ s5,
    const float* __restrict__ s6, unsigned short* __restrict__ dst) {
  const size_t e = ((size_t)blockIdx.x * 256 + threadIdx.x) * 8;
  const float* src;
  size_t off;
  if (e < 9437184) {
    const int i = (int)(e / 3145728);
    src = (i == 0) ? s0 : (i == 1) ? s1 : s2;
    off = e - (size_t)i * 3145728;
  } else {
    const size_t ew = e - 9437184;
    const int i = (int)(ew / 589824);
    src = (i == 0) ? s3 : (i == 1) ? s4 : (i == 2) ? s5 : s6;
    off = ew - (size_t)i * 589824;
  }
  const float4v f0 = *(const float4v*)(src + off);
  const float4v f1 = *(const float4v*)(src + off + 4);
  uint4v u = {pack2(f0.x, f0.y), pack2(f0.z, f0.w), pack2(f1.x, f1.y), pack2(f1.z, f1.w)};
  *(uint4v*)(dst + e) = u;
}

// ---------------------------------------------------------------------------
// Kernel 1: QKV projection (bf16 inputs) + per-head l2 normalization.
// 128x64 tile (1 head/block), BK=64, 4 waves (2x2: wm over 2 row-halves,
// wn over 2 col-halves of 32). DOUBLE-BUFFERED dbuf schedule (r9-proven):
// {vmcnt(0)+barrier -> prefetch ks+1 -> MFMA}. XOR chunk-swizzle both sides.
// which==2 (V) writes TRANSPOSED to vtb [bh][d][t].
// LDS: A0@0 (16K), B0@16384 (8K), A1@24576, B1@40960. 48KB -> 3 blocks/CU.
// grid = (32, 12, 3); block = 256.
// ---------------------------------------------------------------------------
__global__ __launch_bounds__(256) void k_proj(
    const unsigned short* __restrict__ Xb, const unsigned short* __restrict__ Wb,
    unsigned short* __restrict__ qb, unsigned short* __restrict__ kb,
    unsigned short* __restrict__ vtb) {
  __shared__ alignas(16) unsigned char smem[49152];
  float* o_s = (float*)smem;                     // f32[128][68] epilogue alias (34816 B)
  unsigned short* vt_s = (unsigned short*)smem;  // bf16[64][136] V epilogue alias

  const int which = blockIdx.z;
  const int h = blockIdx.y;
  const unsigned short* X = Xb + (size_t)which * 3145728;
  const unsigned short* W = Wb + (size_t)which * 589824 + (size_t)h * 64 * 768;

  const int mbase = blockIdx.x * 128;
  const int tid = threadIdx.x;
  const int lane = tid & 63;
  const int wv = tid >> 6;
  const int wm = wv >> 1, wn = wv & 1;
  const int l15 = lane & 15, l4 = lane >> 4;
  const int srow8 = lane >> 3;
  const int schunk = (lane & 7) ^ srow8;

  f32x4 acc[4][2];
#pragma unroll
  for (int m = 0; m < 4; ++m)
#pragma unroll
    for (int n = 0; n < 2; ++n) acc[m][n] = (f32x4){0.f, 0.f, 0.f, 0.f};

  // prologue: stage ks=0 into buffer 0 (A: 4/wave, B: 2/wave)
#pragma unroll
  for (int i = 0; i < 4; ++i) {
    const int j = wv * 4 + i;
    gload_lds16(X + (size_t)(mbase + j * 8 + srow8) * 768 + schunk * 8, smem + j * 1024);
  }
#pragma unroll
  for (int i = 0; i < 2; ++i) {
    const int j = wv * 2 + i;
    gload_lds16(W + (size_t)(j * 8 + srow8) * 768 + schunk * 8, smem + 16384 + j * 1024);
  }

  for (int ks = 0; ks < 12; ++ks) {
    const int cur = (ks & 1) * 24576;
    // my prefetch done -> barrier -> everyone's prefetch done
    asm volatile("s_waitcnt vmcnt(0)" ::: "memory");
    __builtin_amdgcn_sched_barrier(0);
    __builtin_amdgcn_s_barrier();
    __builtin_amdgcn_sched_barrier(0);
    if (ks < 11) {
      const int nxt = ((ks + 1) & 1) * 24576;
      const int k0n = (ks + 1) * 64;
#pragma unroll
      for (int i = 0; i < 4; ++i) {
        const int j = wv * 4 + i;
        gload_lds16(X + (size_t)(mbase + j * 8 + srow8) * 768 + k0n + schunk * 8,
                    smem + nxt + j * 1024);
      }
#pragma unroll
      for (int i = 0; i < 2; ++i) {
        const int j = wv * 2 + i;
        gload_lds16(W + (size_t)(j * 8 + srow8) * 768 + k0n + schunk * 8,
                    smem + nxt + 16384 + j * 1024);
      }
      __builtin_amdgcn_sched_barrier(0);  // pin prefetch issue before compute
    }
    __builtin_amdgcn_s_setprio(1);
#pragma unroll
    for (int kc = 0; kc < 2; ++kc) {
      const int cx = (kc << 2) | l4;
      short8 ar[4], br[2];
#pragma unroll
      for (int m = 0; m < 4; ++m) {
        const int r = wm * 64 + m * 16 + l15;
        ar[m] = *(const short8*)(smem + cur + r * 128 + ((cx ^ (r & 7)) << 4));
      }
#pragma unroll
      for (int n = 0; n < 2; ++n) {
        const int r = wn * 32 + n * 16 + l15;
        br[n] = *(const short8*)(smem + cur + 16384 + r * 128 + ((cx ^ (r & 7)) << 4));
      }
#pragma unroll
      for (int m = 0; m < 4; ++m)
#pragma unroll
        for (int n = 0; n < 2; ++n) acc[m][n] = MFMA_BF16(ar[m], br[n], acc[m][n]);
    }
    __builtin_amdgcn_s_setprio(0);
  }

  // epilogue: single pass (whole 128x64 head tile)
  const int b = mbase >> 11;
  const int tbase = mbase & 2047;
  const int bh = b * 12 + h;
  __syncthreads();
#pragma unroll
  for (int m = 0; m < 4; ++m)
#pragma unroll
    for (int n = 0; n < 2; ++n)
#pragma unroll
      for (int j = 0; j < 4; ++j)
        o_s[(wm * 64 + m * 16 + l4 * 4 + j) * 68 + wn * 32 + n * 16 + l15] = acc[m][n][j];
  __syncthreads();
  const int row2 = tid >> 1, half = tid & 1;
  float v[32];
  float ss = 0.f;
#pragma unroll
  for (int c = 0; c < 8; ++c) {
    float4v f = *(const float4v*)(o_s + row2 * 68 + half * 32 + c * 4);
    v[c * 4 + 0] = f.x; v[c * 4 + 1] = f.y; v[c * 4 + 2] = f.z; v[c * 4 + 3] = f.w;
    ss += f.x * f.x + f.y * f.y + f.z * f.z + f.w * f.w;
  }
  ss += __shfl_xor(ss, 1);
  const float inv = 1.f / fmaxf(sqrtf(ss), 1e-8f);
  if (which < 2) {
    unsigned short* outp =
        ((which == 0) ? qb : kb) + ((size_t)bh * 2048 + tbase + row2) * 64 + half * 32;
#pragma unroll
    for (int c = 0; c < 4; ++c) {
      uint4v o = {pack2(v[c * 8 + 0] * inv, v[c * 8 + 1] * inv),
                  pack2(v[c * 8 + 2] * inv, v[c * 8 + 3] * inv),
                  pack2(v[c * 8 + 4] * inv, v[c * 8 + 5] * inv),
                  pack2(v[c * 8 + 6] * inv, v[c * 8 + 7] * inv)};
      *(uint4v*)(outp + c * 8) = o;
    }
  } else {
    __syncthreads();  // o_s reads done; vt_s aliases o_s
#pragma unroll
    for (int c = 0; c < 32; ++c)
      vt_s[(half * 32 + c) * 136 + row2] = f2bf(v[c] * inv);
    __syncthreads();
    const int d = tid >> 2, tc = (tid & 3) * 32;
    unsigned short* dst = vtb + ((size_t)bh * 64 + d) * 2048 + tbase + tc;
#pragma unroll
    for (int c = 0; c < 4; ++c)
      *(uint4v*)(dst + c * 8) = *(const uint4v*)(vt_s + d * 136 + tc + c * 8);
  }
}

// ---------------------------------------------------------------------------
// Kernel 2: causal screening attention (ROUND-11 PASSING, unchanged).
// Swapped-S MFMA (reg-dim = keys), Q fragments read directly from global,
// K/V^T DOUBLE-BUFFERED via global_load_lds; full vmcnt(0) drains only.
// Balanced flat grid (heavy+light task pairing).
// LDS: K0 @0, K1 @8192, V0 @16384, V1 @24576, p_s @32768 (9216). 41984 B.
// block = 256 (4 waves, 2x2).
// ---------------------------------------------------------------------------
__global__ __launch_bounds__(256) void k_attn(
    const unsigned short* __restrict__ qb, const unsigned short* __restrict__ kb,
    const unsigned short* __restrict__ vtb, const float* __restrict__ s_v,
    const float* __restrict__ s_r, unsigned short* __restrict__ attn) {
  __shared__ alignas(16) unsigned char smem[41984];
  unsigned short* p_s = (unsigned short*)(smem + 32768);  // [64 q][72 key] bf16
  float* o_s = (float*)smem;                              // [64][68] f32 epilogue alias

  const int bid = blockIdx.x;
  const int ii = bid & 255, jj = bid >> 8;
  const int rank = (jj == 0) ? ii : (jj == 1) ? (511 - ii) : (512 + ii);
  const int qt = 31 - (rank / 24);  // heavy tasks at low rank
  const int bh = rank % 24;
  const int b = bh / 12, h = bh % 12;
  const int qbase = qt * 64;
  const unsigned short* Qp = qb + (size_t)bh * 2048 * 64;
  const unsigned short* Kp = kb + (size_t)bh * 2048 * 64;
  const unsigned short* VTp = vtb + (size_t)bh * 64 * 2048;

  const int tid = threadIdx.x;
  const int lane = tid & 63;
  const int wv = tid >> 6;
  const int wm = wv >> 1, wn = wv & 1;  // S: wm=keys, wn=q. PV: wm=d, wn=q.
  const int l15 = lane & 15, l4 = lane >> 4;
  const int srow8 = lane >> 3;
  const int schunk = (lane & 7) ^ srow8;

  const float w_h = expf(s_v[h]) + 1.0f;          // decay exponent, [2,256]
  const float lr_h = log2f(expf(s_r[h]) + 1.0f);  // log2 of per-head scale

  // prologue: issue kt=0 K/V gloads (loop-top vmcnt(0)+barrier covers them)
#pragma unroll
  for (int i = 0; i < 2; ++i) {
    const int j = wv * 2 + i;
    gload_lds16(Kp + (size_t)(j * 8 + srow8) * 64 + schunk * 8, smem + j * 1024);
    gload_lds16(VTp + (size_t)(j * 8 + srow8) * 2048 + schunk * 8, smem + 16384 + j * 1024);
  }

  // hoist Q fragments (B-operand of swapped S) straight from global (r3-proven)
  short8 qf[2][2];
#pragma unroll
  for (int n = 0; n < 2; ++n)
#pragma unroll
    for (int kc = 0; kc < 2; ++kc)
      qf[n][kc] = *(const short8*)(Qp + (size_t)(qbase + wn * 32 + n * 16 + l15) * 64 + kc * 32 +
                                   l4 * 8);

  f32x4 acc_o[2][2];  // [qi][di]
#pragma unroll
  for (int m = 0; m < 2; ++m)
#pragma unroll
    for (int n = 0; n < 2; ++n) acc_o[m][n] = (f32x4){0.f, 0.f, 0.f, 0.f};

  for (int kt = 0; kt <= qt; ++kt) {
    const int cur = (kt & 1) * 8192;
    // wait current tile's K/V (the only outstanding VMEM = prev prefetch), sync
    asm volatile("s_waitcnt vmcnt(0)" ::: "memory");
    __builtin_amdgcn_sched_barrier(0);
    __builtin_amdgcn_s_barrier();
    __builtin_amdgcn_sched_barrier(0);
    // prefetch kt+1 into the other buffer (all waves past kt-1 reads now)
    if (kt < qt) {
      const int nxt = ((kt + 1) & 1) * 8192;
      const int kb2 = (kt + 1) * 64;
#pragma unroll
      for (int i = 0; i < 2; ++i) {
        const int j = wv * 2 + i;
        gload_lds16(Kp + (size_t)(kb2 + j * 8 + srow8) * 64 + schunk * 8, smem + nxt + j * 1024);
        gload_lds16(VTp + (size_t)(j * 8 + srow8) * 2048 + kb2 + schunk * 8,
                    smem + 16384 + nxt + j * 1024);
      }
      __builtin_amdgcn_sched_barrier(0);  // pin prefetch issue before compute
    }
    // S^T = K Q^T : rows = keys, cols = q
    f32x4 s_acc[2][2];
#pragma unroll
    for (int m = 0; m < 2; ++m)
#pragma unroll
      for (int n = 0; n < 2; ++n) s_acc[m][n] = (f32x4){0.f, 0.f, 0.f, 0.f};
    __builtin_amdgcn_s_setprio(1);
#pragma unroll
    for (int kc = 0; kc < 2; ++kc) {
      const int cx = (kc << 2) | l4;
      const int r0 = wm * 32 + l15, r1 = wm * 32 + 16 + l15;
      short8 a0 = *(const short8*)(smem + cur + r0 * 128 + ((cx ^ (r0 & 7)) << 4));
      short8 a1 = *(const short8*)(smem + cur + r1 * 128 + ((cx ^ (r1 & 7)) << 4));
      s_acc[0][0] = MFMA_BF16(a0, qf[0][kc], s_acc[0][0]);
      s_acc[0][1] = MFMA_BF16(a0, qf[1][kc], s_acc[0][1]);
      s_acc[1][0] = MFMA_BF16(a1, qf[0][kc], s_acc[1][0]);
      s_acc[1][1] = MFMA_BF16(a1, qf[1][kc], s_acc[1][1]);
    }
    __builtin_amdgcn_s_setprio(0);
    // alpha = r * clamp((s+1)/2)^w ; frag reg-dim = consecutive keys -> b64 stores
    const bool diag = (kt == qt);
#pragma unroll
    for (int m = 0; m < 2; ++m)
#pragma unroll
      for (int n = 0; n < 2; ++n) {
        const int lkb = wm * 32 + m * 16 + l4 * 4;  // key base (reg dim)
        const int lq = wn * 32 + n * 16 + l15;      // q (lane dim)
        float av[4];
#pragma unroll
        for (int t = 0; t < 4; ++t) {
          const float base = __builtin_amdgcn_fmed3f(fmaf(s_acc[m][n][t], 0.5f, 0.5f), 0.f, 1.f);
          float a = __builtin_amdgcn_exp2f(fmaf(w_h, __builtin_amdgcn_logf(base), lr_h));
          if (diag && (lkb + t) > lq) a = 0.f;
          av[t] = a;
        }
        uint2v u = {pack2(av[0], av[1]), pack2(av[2], av[3])};
        *(uint2v*)(p_s + lq * 72 + lkb) = u;
      }
    // drain LDS writes of P, then sync (raw barrier: keep prefetch in flight)
    asm volatile("s_waitcnt lgkmcnt(0)" ::: "memory");
    __builtin_amdgcn_sched_barrier(0);
    __builtin_amdgcn_s_barrier();
    __builtin_amdgcn_sched_barrier(0);
    // O += P V : A = P[q][key] (padded b128 rows), B = V^T[d][key] (swizzled)
    __builtin_amdgcn_s_setprio(1);
#pragma unroll
    for (int kc = 0; kc < 2; ++kc) {
      const int cx = (kc << 2) | l4;
      const int r0 = wm * 32 + l15, r1 = wm * 32 + 16 + l15;
      short8 pa0 = *(const short8*)(p_s + (wn * 32 + l15) * 72 + kc * 32 + l4 * 8);
      short8 pa1 = *(const short8*)(p_s + (wn * 32 + 16 + l15) * 72 + kc * 32 + l4 * 8);
      short8 vb0 = *(const short8*)(smem + 16384 + cur + r0 * 128 + ((cx ^ (r0 & 7)) << 4));
      short8 vb1 = *(const short8*)(smem + 16384 + cur + r1 * 128 + ((cx ^ (r1 & 7)) << 4));
      acc_o[0][0] = MFMA_BF16(pa0, vb0, acc_o[0][0]);
      acc_o[0][1] = MFMA_BF16(pa0, vb1, acc_o[0][1]);
      acc_o[1][0] = MFMA_BF16(pa1, vb0, acc_o[1][0]);
      acc_o[1][1] = MFMA_BF16(pa1, vb1, acc_o[1][1]);
    }
    __builtin_amdgcn_s_setprio(0);
  }
  __syncthreads();
#pragma unroll
  for (int qi = 0; qi < 2; ++qi)
#pragma unroll
    for (int di = 0; di < 2; ++di)
#pragma unroll
      for (int j = 0; j < 4; ++j)
        o_s[(wn * 32 + qi * 16 + l4 * 4 + j) * 68 + wm * 32 + di * 16 + l15] = acc_o[qi][di][j];
  __syncthreads();
  // TanhNorm: out = tanh(n) * out / (n + eps)
  {
    const int row = tid >> 2, q4 = tid & 3;
    float vals[16];
    float ss = 0.f;
#pragma unroll
    for (int j = 0; j < 16; ++j) {
      vals[j] = o_s[row * 68 + q4 * 16 + j];
      ss += vals[j] * vals[j];
    }
    ss += __shfl_xor(ss, 1);
    ss += __shfl_xor(ss, 2);
    const float nrm = sqrtf(ss);
    const float sc = tanhf(nrm) / (nrm + 1e-8f);
    unsigned short* dst = attn + (size_t)(b * 2048 + qbase + row) * 768 + h * 64 + q4 * 16;
    uint4v o0 = {pack2(vals[0] * sc, vals[1] * sc), pack2(vals[2] * sc, vals[3] * sc),
                 pack2(vals[4] * sc, vals[5] * sc), pack2(vals[6] * sc, vals[7] * sc)};
    uint4v o1 = {pack2(vals[8] * sc, vals[9] * sc), pack2(vals[10] * sc, vals[11] * sc),
                 pack2(vals[12] * sc, vals[13] * sc), pack2(vals[14] * sc, vals[15] * sc)};
    *(uint4v*)(dst) = o0;
    *(uint4v*)(dst + 8) = o1;
  }
}

// ---------------------------------------------------------------------------
// Kernel 3: out = attn[4096x768](bf16) @ Wo^T(bf16) -> f32. 128x64 tile
// (r14-proven). Same dbuf schedule. A frags 4, B frags 2, acc[4][2].
// LDS: A0@0 (16K), B0@16384 (8K), A1@24576, B1@40960. grid (32,12); block 256.
// ---------------------------------------------------------------------------
__global__ __launch_bounds__(256) void k_outproj(const unsigned short* __restrict__ attn,
                                                 const unsigned short* __restrict__ Wob,
                                                 float* __restrict__ out) {
  __shared__ alignas(16) unsigned char smem[49152];
  const int mbase = blockIdx.x * 128;
  const int nbase = blockIdx.y * 64;
  const int tid = threadIdx.x;
  const int lane = tid & 63;
  const int wv = tid >> 6;
  const int wm = wv >> 1, wn = wv & 1;
  const int l15 = lane & 15, l4 = lane >> 4;
  const int srow8 = lane >> 3;
  const int schunk = (lane & 7) ^ srow8;

  f32x4 acc[4][2];
#pragma unroll
  for (int m = 0; m < 4; ++m)
#pragma unroll
    for (int n = 0; n < 2; ++n) acc[m][n] = (f32x4){0.f, 0.f, 0.f, 0.f};

  // prologue: stage ks=0 into buffer 0 (A: 4 instrs/wave, B: 2 instrs/wave)
#pragma unroll
  for (int i = 0; i < 4; ++i) {
    const int j = wv * 4 + i;
    gload_lds16(attn + (size_t)(mbase + j * 8 + srow8) * 768 + schunk * 8, smem + j * 1024);
  }
#pragma unroll
  for (int i = 0; i < 2; ++i) {
    const int j = wv * 2 + i;
    gload_lds16(Wob + (size_t)(nbase + j * 8 + srow8) * 768 + schunk * 8,
                smem + 16384 + j * 1024);
  }

  for (int ks = 0; ks < 12; ++ks) {
    const int cur = (ks & 1) * 24576;
    asm volatile("s_waitcnt vmcnt(0)" ::: "memory");
    __builtin_amdgcn_sched_barrier(0);
    __builtin_amdgcn_s_barrier();
    __builtin_amdgcn_sched_barrier(0);
    if (ks < 11) {
      const int nxt = ((ks + 1) & 1) * 24576;
      const int k0n = (ks + 1) * 64;
#pragma unroll
      for (int i = 0; i < 4; ++i) {
        const int j = wv * 4 + i;
        gload_lds16(attn + (size_t)(mbase + j * 8 + srow8) * 768 + k0n + schunk * 8,
                    smem + nxt + j * 1024);
      }
#pragma unroll
      for (int i = 0; i < 2; ++i) {
        const int j = wv * 2 + i;
        gload_lds16(Wob + (size_t)(nbase + j * 8 + srow8) * 768 + k0n + schunk * 8,
                    smem + nxt + 16384 + j * 1024);
      }
      __builtin_amdgcn_sched_barrier(0);
    }
    __builtin_amdgcn_s_setprio(1);
#pragma unroll
    for (int kc = 0; kc < 2; ++kc) {
      const int cx = (kc << 2) | l4;
      short8 ar[4], br[2];
#pragma unroll
      for (int m = 0; m < 4; ++m) {
        const int r = wm * 64 + m * 16 + l15;
        ar[m] = *(const short8*)(smem + cur + r * 128 + ((cx ^ (r & 7)) << 4));
      }
#pragma unroll
      for (int n = 0; n < 2; ++n) {
        const int r = wn * 32 + n * 16 + l15;
        br[n] = *(const short8*)(smem + cur + 16384 + r * 128 + ((cx ^ (r & 7)) << 4));
      }
#pragma unroll
      for (int m = 0; m < 4; ++m)
#pragma unroll
        for (int n = 0; n < 2; ++n) acc[m][n] = MFMA_BF16(ar[m], br[n], acc[m][n]);
    }
    __builtin_amdgcn_s_setprio(0);
  }
#pragma unroll
  for (int m = 0; m < 4; ++m)
#pragma unroll
    for (int n = 0; n < 2; ++n)
#pragma unroll
      for (int j = 0; j < 4; ++j)
        out[(size_t)(mbase + wm * 64 + m * 16 + l4 * 4 + j) * 768 + nbase + wn * 32 + n * 16 +
            l15] = acc[m][n][j];
}

extern "C" void kernel_launch(void* const* d_in, const int* in_sizes, int n_in, void* d_out,
                              int out_size, void* d_ws, size_t ws_size, hipStream_t stream) {
  (void)in_sizes;
  (void)n_in;
  (void)out_size;
  (void)ws_size;
  const float* query = (const float*)d_in[0];
  const float* key = (const float*)d_in[1];
  const float* value = (const float*)d_in[2];
  const float* Wq = (const float*)d_in[3];
  const float* Wk = (const float*)d_in[4];
  const float* Wv = (const float*)d_in[5];
  const float* Wo = (const float*)d_in[6];
  const float* s_v = (const float*)d_in[7];
  const float* s_r = (const float*)d_in[8];
  float* out = (float*)d_out;

  // ws layout (bf16 elems): [Xb 3x3145728 | Wb 4x589824 | qb | kb | vtb]
  // attn aliases Xb (dead after k_proj). Total 42.5 MB.
  unsigned short* cvt = (unsigned short*)d_ws;
  unsigned short* Xb = cvt;
  unsigned short* Wb = cvt + 9437184;
  unsigned short* qb = cvt + 11796480;
  unsigned short* kb = qb + 3145728;
  unsigned short* vtb = kb + 3145728;
  unsigned short* attn = cvt;

  k_cvt<<<5760, 256, 0, stream>>>(query, key, value, Wq, Wk, Wv, Wo, cvt);
  k_proj<<<dim3(32, 12, 3), 256, 0, stream>>>(Xb, Wb, qb, kb, vtb);
  k_attn<<<dim3(768), 256, 0, stream>>>(qb, kb, vtb, s_v, s_r, attn);
  k_outproj<<<dim3(32, 12), 256, 0, stream>>>(attn, Wb + 3 * 589824, out);
}

// Round 16
// 80.537 us; speedup vs baseline: 1.2842x; 1.0260x over previous
//
#include <hip/hip_runtime.h>
#include <hip/hip_bf16.h>
#include <math.h>

// ScreeningAttention: B=2, T=2048, D_MODEL=768, H=12, D=64
// Round 16 = round-15 (82.6us best) + k_attn re-waved: 512-thread blocks
// (8 waves, wave = (key/d-half, q-quarter)) -> 24 waves/CU resident (was 12).
// Same tile size, same proven dbuf sync schedule, same pairing grid.
// k_cvt -> k_proj (128x64, r15-proven) -> k_attn (8-wave) -> k_outproj
// (128x64, r14-proven).
// LESSONS: v_cvt_pk_bf16_f32 asm pack = correctness bug (r4/6/7). A-direct /
// fused-cvt k_proj = regression (r10 uncoalesced, r12 serial path). k_attn
// strip-tiling = regression (r13: L2 locality loss, FETCH 13->79MB).

typedef __attribute__((ext_vector_type(8))) short short8;     // 8 bf16, MFMA A/B frag
typedef __attribute__((ext_vector_type(4))) float f32x4;      // MFMA C/D frag
typedef __attribute__((ext_vector_type(4))) unsigned int uint4v;
typedef __attribute__((ext_vector_type(2))) unsigned int uint2v;
typedef __attribute__((ext_vector_type(4))) float float4v;

#define MFMA_BF16(a, b, c) __builtin_amdgcn_mfma_f32_16x16x32_bf16((a), (b), (c), 0, 0, 0)

// round-to-nearest-even f32->bf16, bit-manip (round-3-proven).
static __device__ __forceinline__ unsigned short f2bf(float f) {
  union { float f; unsigned u; } v; v.f = f;
  unsigned r = v.u + 0x7FFFu + ((v.u >> 16) & 1u);
  return (unsigned short)(r >> 16);
}
static __device__ __forceinline__ unsigned pack2(float a, float b) {
  return (unsigned)f2bf(a) | ((unsigned)f2bf(b) << 16);
}
// async global->LDS, 16B per lane. LDS dest = wave-uniform base + lane*16.
static __device__ __forceinline__ void gload_lds16(const void* g, void* l) {
  __builtin_amdgcn_global_load_lds((const __attribute__((address_space(1))) unsigned int*)g,
                                   (__attribute__((address_space(3))) unsigned int*)l, 16, 0, 0);
}

// ---------------------------------------------------------------------------
// Kernel 0: convert Xq,Xk,Xv (3x3145728) + Wq,Wk,Wv,Wo (4x589824) f32->bf16
// into one contiguous bf16 region. grid 5760x256, 8 elems/thread.
// ---------------------------------------------------------------------------
__global__ __launch_bounds__(256) void k_cvt(
    const float* __restrict__ s0, const float* __restrict__ s1, const float* __restrict__ s2,
    const float* __restrict__ s3, const float* __restrict__ s4, const float* __restrict__ s5,
    const float* __restrict__ s6, unsigned short* __restrict__ dst) {
  const size_t e = ((size_t)blockIdx.x * 256 + threadIdx.x) * 8;
  const float* src;
  size_t off;
  if (e < 9437184) {
    const int i = (int)(e / 3145728);
    src = (i == 0) ? s0 : (i == 1) ? s1 : s2;
    off = e - (size_t)i * 3145728;
  } else {
    const size_t ew = e - 9437184;
    const int i = (int)(ew / 589824);
    src = (i == 0) ? s3 : (i == 1) ? s4 : (i == 2) ? s5 : s6;
    off = ew - (size_t)i * 589824;
  }
  const float4v f0 = *(const float4v*)(src + off);
  const float4v f1 = *(const float4v*)(src + off + 4);
  uint4v u = {pack2(f0.x, f0.y), pack2(f0.z, f0.w), pack2(f1.x, f1.y), pack2(f1.z, f1.w)};
  *(uint4v*)(dst + e) = u;
}

// ---------------------------------------------------------------------------
// Kernel 1: QKV projection (bf16 inputs) + per-head l2 normalization.
// 128x64 tile (1 head/block), dbuf schedule, XOR chunk-swizzle (r15-proven).
// which==2 (V) writes TRANSPOSED to vtb [bh][d][t].
// LDS: A0@0 (16K), B0@16384 (8K), A1@24576, B1@40960. 48KB -> 3 blocks/CU.
// grid = (32, 12, 3); block = 256.
// ---------------------------------------------------------------------------
__global__ __launch_bounds__(256) void k_proj(
    const unsigned short* __restrict__ Xb, const unsigned short* __restrict__ Wb,
    unsigned short* __restrict__ qb, unsigned short* __restrict__ kb,
    unsigned short* __restrict__ vtb) {
  __shared__ alignas(16) unsigned char smem[49152];
  float* o_s = (float*)smem;                     // f32[128][68] epilogue alias (34816 B)
  unsigned short* vt_s = (unsigned short*)smem;  // bf16[64][136] V epilogue alias

  const int which = blockIdx.z;
  const int h = blockIdx.y;
  const unsigned short* X = Xb + (size_t)which * 3145728;
  const unsigned short* W = Wb + (size_t)which * 589824 + (size_t)h * 64 * 768;

  const int mbase = blockIdx.x * 128;
  const int tid = threadIdx.x;
  const int lane = tid & 63;
  const int wv = tid >> 6;
  const int wm = wv >> 1, wn = wv & 1;
  const int l15 = lane & 15, l4 = lane >> 4;
  const int srow8 = lane >> 3;
  const int schunk = (lane & 7) ^ srow8;

  f32x4 acc[4][2];
#pragma unroll
  for (int m = 0; m < 4; ++m)
#pragma unroll
    for (int n = 0; n < 2; ++n) acc[m][n] = (f32x4){0.f, 0.f, 0.f, 0.f};

  // prologue: stage ks=0 into buffer 0 (A: 4/wave, B: 2/wave)
#pragma unroll
  for (int i = 0; i < 4; ++i) {
    const int j = wv * 4 + i;
    gload_lds16(X + (size_t)(mbase + j * 8 + srow8) * 768 + schunk * 8, smem + j * 1024);
  }
#pragma unroll
  for (int i = 0; i < 2; ++i) {
    const int j = wv * 2 + i;
    gload_lds16(W + (size_t)(j * 8 + srow8) * 768 + schunk * 8, smem + 16384 + j * 1024);
  }

  for (int ks = 0; ks < 12; ++ks) {
    const int cur = (ks & 1) * 24576;
    asm volatile("s_waitcnt vmcnt(0)" ::: "memory");
    __builtin_amdgcn_sched_barrier(0);
    __builtin_amdgcn_s_barrier();
    __builtin_amdgcn_sched_barrier(0);
    if (ks < 11) {
      const int nxt = ((ks + 1) & 1) * 24576;
      const int k0n = (ks + 1) * 64;
#pragma unroll
      for (int i = 0; i < 4; ++i) {
        const int j = wv * 4 + i;
        gload_lds16(X + (size_t)(mbase + j * 8 + srow8) * 768 + k0n + schunk * 8,
                    smem + nxt + j * 1024);
      }
#pragma unroll
      for (int i = 0; i < 2; ++i) {
        const int j = wv * 2 + i;
        gload_lds16(W + (size_t)(j * 8 + srow8) * 768 + k0n + schunk * 8,
                    smem + nxt + 16384 + j * 1024);
      }
      __builtin_amdgcn_sched_barrier(0);  // pin prefetch issue before compute
    }
    __builtin_amdgcn_s_setprio(1);
#pragma unroll
    for (int kc = 0; kc < 2; ++kc) {
      const int cx = (kc << 2) | l4;
      short8 ar[4], br[2];
#pragma unroll
      for (int m = 0; m < 4; ++m) {
        const int r = wm * 64 + m * 16 + l15;
        ar[m] = *(const short8*)(smem + cur + r * 128 + ((cx ^ (r & 7)) << 4));
      }
#pragma unroll
      for (int n = 0; n < 2; ++n) {
        const int r = wn * 32 + n * 16 + l15;
        br[n] = *(const short8*)(smem + cur + 16384 + r * 128 + ((cx ^ (r & 7)) << 4));
      }
#pragma unroll
      for (int m = 0; m < 4; ++m)
#pragma unroll
        for (int n = 0; n < 2; ++n) acc[m][n] = MFMA_BF16(ar[m], br[n], acc[m][n]);
    }
    __builtin_amdgcn_s_setprio(0);
  }

  // epilogue: single pass (whole 128x64 head tile)
  const int b = mbase >> 11;
  const int tbase = mbase & 2047;
  const int bh = b * 12 + h;
  __syncthreads();
#pragma unroll
  for (int m = 0; m < 4; ++m)
#pragma unroll
    for (int n = 0; n < 2; ++n)
#pragma unroll
      for (int j = 0; j < 4; ++j)
        o_s[(wm * 64 + m * 16 + l4 * 4 + j) * 68 + wn * 32 + n * 16 + l15] = acc[m][n][j];
  __syncthreads();
  const int row2 = tid >> 1, half = tid & 1;
  float v[32];
  float ss = 0.f;
#pragma unroll
  for (int c = 0; c < 8; ++c) {
    float4v f = *(const float4v*)(o_s + row2 * 68 + half * 32 + c * 4);
    v[c * 4 + 0] = f.x; v[c * 4 + 1] = f.y; v[c * 4 + 2] = f.z; v[c * 4 + 3] = f.w;
    ss += f.x * f.x + f.y * f.y + f.z * f.z + f.w * f.w;
  }
  ss += __shfl_xor(ss, 1);
  const float inv = 1.f / fmaxf(sqrtf(ss), 1e-8f);
  if (which < 2) {
    unsigned short* outp =
        ((which == 0) ? qb : kb) + ((size_t)bh * 2048 + tbase + row2) * 64 + half * 32;
#pragma unroll
    for (int c = 0; c < 4; ++c) {
      uint4v o = {pack2(v[c * 8 + 0] * inv, v[c * 8 + 1] * inv),
                  pack2(v[c * 8 + 2] * inv, v[c * 8 + 3] * inv),
                  pack2(v[c * 8 + 4] * inv, v[c * 8 + 5] * inv),
                  pack2(v[c * 8 + 6] * inv, v[c * 8 + 7] * inv)};
      *(uint4v*)(outp + c * 8) = o;
    }
  } else {
    __syncthreads();  // o_s reads done; vt_s aliases o_s
#pragma unroll
    for (int c = 0; c < 32; ++c)
      vt_s[(half * 32 + c) * 136 + row2] = f2bf(v[c] * inv);
    __syncthreads();
    const int d = tid >> 2, tc = (tid & 3) * 32;
    unsigned short* dst = vtb + ((size_t)bh * 64 + d) * 2048 + tbase + tc;
#pragma unroll
    for (int c = 0; c < 4; ++c)
      *(uint4v*)(dst + c * 8) = *(const uint4v*)(vt_s + d * 136 + tc + c * 8);
  }
}

// ---------------------------------------------------------------------------
// Kernel 2: causal screening attention, 8-WAVE blocks (512 threads).
// Wave (wm,wn) = (wv>>2, wv&3): keys/d half wm*32+{0,16}, q-quarter wn*16.
// Same 64x64 tile, same proven dbuf schedule (full vmcnt(0) drains; lgkm+
// barrier around p_s), same heavy/light pairing grid. 24 waves/CU resident.
// LDS: K0 @0, K1 @8192, V0 @16384, V1 @24576, p_s @32768 (9216). 41984 B.
// grid = 768; block = 512.
// ---------------------------------------------------------------------------
__global__ __launch_bounds__(512) void k_attn(
    const unsigned short* __restrict__ qb, const unsigned short* __restrict__ kb,
    const unsigned short* __restrict__ vtb, const float* __restrict__ s_v,
    const float* __restrict__ s_r, unsigned short* __restrict__ attn) {
  __shared__ alignas(16) unsigned char smem[41984];
  unsigned short* p_s = (unsigned short*)(smem + 32768);  // [64 q][72 key] bf16
  float* o_s = (float*)smem;                              // [64][68] f32 epilogue alias

  const int bid = blockIdx.x;
  const int ii = bid & 255, jj = bid >> 8;
  const int rank = (jj == 0) ? ii : (jj == 1) ? (511 - ii) : (512 + ii);
  const int qt = 31 - (rank / 24);  // heavy tasks at low rank
  const int bh = rank % 24;
  const int b = bh / 12, h = bh % 12;
  const int qbase = qt * 64;
  const unsigned short* Qp = qb + (size_t)bh * 2048 * 64;
  const unsigned short* Kp = kb + (size_t)bh * 2048 * 64;
  const unsigned short* VTp = vtb + (size_t)bh * 64 * 2048;

  const int tid = threadIdx.x;
  const int lane = tid & 63;
  const int wv = tid >> 6;              // 0..7
  const int wm = wv >> 2, wn = wv & 3;  // S: wm=key-half, wn=q-quarter. PV: wm=d-half.
  const int l15 = lane & 15, l4 = lane >> 4;
  const int srow8 = lane >> 3;
  const int schunk = (lane & 7) ^ srow8;

  const float w_h = expf(s_v[h]) + 1.0f;          // decay exponent, [2,256]
  const float lr_h = log2f(expf(s_r[h]) + 1.0f);  // log2 of per-head scale

  // prologue: issue kt=0 K/V gloads, 1 instr/wave each (8 waves x 8 rows)
  gload_lds16(Kp + (size_t)(wv * 8 + srow8) * 64 + schunk * 8, smem + wv * 1024);
  gload_lds16(VTp + (size_t)(wv * 8 + srow8) * 2048 + schunk * 8, smem + 16384 + wv * 1024);

  // hoist Q fragments (B-operand of swapped S) straight from global
  short8 qf[2];
#pragma unroll
  for (int kc = 0; kc < 2; ++kc)
    qf[kc] = *(const short8*)(Qp + (size_t)(qbase + wn * 16 + l15) * 64 + kc * 32 + l4 * 8);

  f32x4 acc_o[2];  // [d-half within wave's 32-wide d group]
#pragma unroll
  for (int m = 0; m < 2; ++m) acc_o[m] = (f32x4){0.f, 0.f, 0.f, 0.f};

  for (int kt = 0; kt <= qt; ++kt) {
    const int cur = (kt & 1) * 8192;
    // wait current tile's K/V (the only outstanding VMEM = prev prefetch), sync
    asm volatile("s_waitcnt vmcnt(0)" ::: "memory");
    __builtin_amdgcn_sched_barrier(0);
    __builtin_amdgcn_s_barrier();
    __builtin_amdgcn_sched_barrier(0);
    // prefetch kt+1 into the other buffer
    if (kt < qt) {
      const int nxt = ((kt + 1) & 1) * 8192;
      const int kb2 = (kt + 1) * 64;
      gload_lds16(Kp + (size_t)(kb2 + wv * 8 + srow8) * 64 + schunk * 8, smem + nxt + wv * 1024);
      gload_lds16(VTp + (size_t)(wv * 8 + srow8) * 2048 + kb2 + schunk * 8,
                  smem + 16384 + nxt + wv * 1024);
      __builtin_amdgcn_sched_barrier(0);  // pin prefetch issue before compute
    }
    // S^T = K Q^T : rows = keys (wave's 32-key half), cols = q (wave's 16-q)
    f32x4 s_acc[2];
#pragma unroll
    for (int m = 0; m < 2; ++m) s_acc[m] = (f32x4){0.f, 0.f, 0.f, 0.f};
    __builtin_amdgcn_s_setprio(1);
#pragma unroll
    for (int kc = 0; kc < 2; ++kc) {
      const int cx = (kc << 2) | l4;
      const int r0 = wm * 32 + l15, r1 = wm * 32 + 16 + l15;
      short8 a0 = *(const short8*)(smem + cur + r0 * 128 + ((cx ^ (r0 & 7)) << 4));
      short8 a1 = *(const short8*)(smem + cur + r1 * 128 + ((cx ^ (r1 & 7)) << 4));
      s_acc[0] = MFMA_BF16(a0, qf[kc], s_acc[0]);
      s_acc[1] = MFMA_BF16(a1, qf[kc], s_acc[1]);
    }
    __builtin_amdgcn_s_setprio(0);
    // alpha = r * clamp((s+1)/2)^w ; frag reg-dim = consecutive keys -> b64 stores
    const bool diag = (kt == qt);
#pragma unroll
    for (int m = 0; m < 2; ++m) {
      const int lkb = wm * 32 + m * 16 + l4 * 4;  // key base (reg dim)
      const int lq = wn * 16 + l15;               // q (lane dim)
      float av[4];
#pragma unroll
      for (int t = 0; t < 4; ++t) {
        const float base = __builtin_amdgcn_fmed3f(fmaf(s_acc[m][t], 0.5f, 0.5f), 0.f, 1.f);
        float a = __builtin_amdgcn_exp2f(fmaf(w_h, __builtin_amdgcn_logf(base), lr_h));
        if (diag && (lkb + t) > lq) a = 0.f;
        av[t] = a;
      }
      uint2v u = {pack2(av[0], av[1]), pack2(av[2], av[3])};
      *(uint2v*)(p_s + lq * 72 + lkb) = u;
    }
    // drain LDS writes of P, then sync (raw barrier: keep prefetch in flight)
    asm volatile("s_waitcnt lgkmcnt(0)" ::: "memory");
    __builtin_amdgcn_sched_barrier(0);
    __builtin_amdgcn_s_barrier();
    __builtin_amdgcn_sched_barrier(0);
    // O += P V : A = P[q][key] (padded b128 rows), B = V^T[d][key] (swizzled)
    __builtin_amdgcn_s_setprio(1);
#pragma unroll
    for (int kc = 0; kc < 2; ++kc) {
      const int cx = (kc << 2) | l4;
      const int r0 = wm * 32 + l15, r1 = wm * 32 + 16 + l15;
      short8 pa = *(const short8*)(p_s + (wn * 16 + l15) * 72 + kc * 32 + l4 * 8);
      short8 vb0 = *(const short8*)(smem + 16384 + cur + r0 * 128 + ((cx ^ (r0 & 7)) << 4));
      short8 vb1 = *(const short8*)(smem + 16384 + cur + r1 * 128 + ((cx ^ (r1 & 7)) << 4));
      acc_o[0] = MFMA_BF16(pa, vb0, acc_o[0]);
      acc_o[1] = MFMA_BF16(pa, vb1, acc_o[1]);
    }
    __builtin_amdgcn_s_setprio(0);
  }
  __syncthreads();
#pragma unroll
  for (int m = 0; m < 2; ++m)
#pragma unroll
    for (int j = 0; j < 4; ++j)
      o_s[(wn * 16 + l4 * 4 + j) * 68 + wm * 32 + m * 16 + l15] = acc_o[m][j];
  __syncthreads();
  // TanhNorm: out = tanh(n) * out / (n + eps). 8 threads/row x 8 d each.
  {
    const int row = tid >> 3, d8 = (tid & 7) * 8;
    float vals[8];
    float ss = 0.f;
#pragma unroll
    for (int c = 0; c < 2; ++c) {
      float4v f = *(const float4v*)(o_s + row * 68 + d8 + c * 4);
      vals[c * 4 + 0] = f.x; vals[c * 4 + 1] = f.y; vals[c * 4 + 2] = f.z; vals[c * 4 + 3] = f.w;
      ss += f.x * f.x + f.y * f.y + f.z * f.z + f.w * f.w;
    }
    ss += __shfl_xor(ss, 1);
    ss += __shfl_xor(ss, 2);
    ss += __shfl_xor(ss, 4);
    const float nrm = sqrtf(ss);
    const float sc = tanhf(nrm) / (nrm + 1e-8f);
    unsigned short* dst = attn + (size_t)(b * 2048 + qbase + row) * 768 + h * 64 + d8;
    uint4v o = {pack2(vals[0] * sc, vals[1] * sc), pack2(vals[2] * sc, vals[3] * sc),
                pack2(vals[4] * sc, vals[5] * sc), pack2(vals[6] * sc, vals[7] * sc)};
    *(uint4v*)(dst) = o;
  }
}

// ---------------------------------------------------------------------------
// Kernel 3: out = attn[4096x768](bf16) @ Wo^T(bf16) -> f32. 128x64 tile
// (r14-proven). Same dbuf schedule. A frags 4, B frags 2, acc[4][2].
// LDS: A0@0 (16K), B0@16384 (8K), A1@24576, B1@40960. grid (32,12); block 256.
// ---------------------------------------------------------------------------
__global__ __launch_bounds__(256) void k_outproj(const unsigned short* __restrict__ attn,
                                                 const unsigned short* __restrict__ Wob,
                                                 float* __restrict__ out) {
  __shared__ alignas(16) unsigned char smem[49152];
  const int mbase = blockIdx.x * 128;
  const int nbase = blockIdx.y * 64;
  const int tid = threadIdx.x;
  const int lane = tid & 63;
  const int wv = tid >> 6;
  const int wm = wv >> 1, wn = wv & 1;
  const int l15 = lane & 15, l4 = lane >> 4;
  const int srow8 = lane >> 3;
  const int schunk = (lane & 7) ^ srow8;

  f32x4 acc[4][2];
#pragma unroll
  for (int m = 0; m < 4; ++m)
#pragma unroll
    for (int n = 0; n < 2; ++n) acc[m][n] = (f32x4){0.f, 0.f, 0.f, 0.f};

  // prologue: stage ks=0 into buffer 0 (A: 4 instrs/wave, B: 2 instrs/wave)
#pragma unroll
  for (int i = 0; i < 4; ++i) {
    const int j = wv * 4 + i;
    gload_lds16(attn + (size_t)(mbase + j * 8 + srow8) * 768 + schunk * 8, smem + j * 1024);
  }
#pragma unroll
  for (int i = 0; i < 2; ++i) {
    const int j = wv * 2 + i;
    gload_lds16(Wob + (size_t)(nbase + j * 8 + srow8) * 768 + schunk * 8,
                smem + 16384 + j * 1024);
  }

  for (int ks = 0; ks < 12; ++ks) {
    const int cur = (ks & 1) * 24576;
    asm volatile("s_waitcnt vmcnt(0)" ::: "memory");
    __builtin_amdgcn_sched_barrier(0);
    __builtin_amdgcn_s_barrier();
    __builtin_amdgcn_sched_barrier(0);
    if (ks < 11) {
      const int nxt = ((ks + 1) & 1) * 24576;
      const int k0n = (ks + 1) * 64;
#pragma unroll
      for (int i = 0; i < 4; ++i) {
        const int j = wv * 4 + i;
        gload_lds16(attn + (size_t)(mbase + j * 8 + srow8) * 768 + k0n + schunk * 8,
                    smem + nxt + j * 1024);
      }
#pragma unroll
      for (int i = 0; i < 2; ++i) {
        const int j = wv * 2 + i;
        gload_lds16(Wob + (size_t)(nbase + j * 8 + srow8) * 768 + k0n + schunk * 8,
                    smem + nxt + 16384 + j * 1024);
      }
      __builtin_amdgcn_sched_barrier(0);
    }
    __builtin_amdgcn_s_setprio(1);
#pragma unroll
    for (int kc = 0; kc < 2; ++kc) {
      const int cx = (kc << 2) | l4;
      short8 ar[4], br[2];
#pragma unroll
      for (int m = 0; m < 4; ++m) {
        const int r = wm * 64 + m * 16 + l15;
        ar[m] = *(const short8*)(smem + cur + r * 128 + ((cx ^ (r & 7)) << 4));
      }
#pragma unroll
      for (int n = 0; n < 2; ++n) {
        const int r = wn * 32 + n * 16 + l15;
        br[n] = *(const short8*)(smem + cur + 16384 + r * 128 + ((cx ^ (r & 7)) << 4));
      }
#pragma unroll
      for (int m = 0; m < 4; ++m)
#pragma unroll
        for (int n = 0; n < 2; ++n) acc[m][n] = MFMA_BF16(ar[m], br[n], acc[m][n]);
    }
    __builtin_amdgcn_s_setprio(0);
  }
#pragma unroll
  for (int m = 0; m < 4; ++m)
#pragma unroll
    for (int n = 0; n < 2; ++n)
#pragma unroll
      for (int j = 0; j < 4; ++j)
        out[(size_t)(mbase + wm * 64 + m * 16 + l4 * 4 + j) * 768 + nbase + wn * 32 + n * 16 +
            l15] = acc[m][n][j];
}

extern "C" void kernel_launch(void* const* d_in, const int* in_sizes, int n_in, void* d_out,
                              int out_size, void* d_ws, size_t ws_size, hipStream_t stream) {
  (void)in_sizes;
  (void)n_in;
  (void)out_size;
  (void)ws_size;
  const float* query = (const float*)d_in[0];
  const float* key = (const float*)d_in[1];
  const float* value = (const float*)d_in[2];
  const float* Wq = (const float*)d_in[3];
  const float* Wk = (const float*)d_in[4];
  const float* Wv = (const float*)d_in[5];
  const float* Wo = (const float*)d_in[6];
  const float* s_v = (const float*)d_in[7];
  const float* s_r = (const float*)d_in[8];
  float* out = (float*)d_out;

  // ws layout (bf16 elems): [Xb 3x3145728 | Wb 4x589824 | qb | kb | vtb]
  // attn aliases Xb (dead after k_proj). Total 42.5 MB.
  unsigned short* cvt = (unsigned short*)d_ws;
  unsigned short* Xb = cvt;
  unsigned short* Wb = cvt + 9437184;
  unsigned short* qb = cvt + 11796480;
  unsigned short* kb = qb + 3145728;
  unsigned short* vtb = kb + 3145728;
  unsigned short* attn = cvt;

  k_cvt<<<5760, 256, 0, stream>>>(query, key, value, Wq, Wk, Wv, Wo, cvt);
  k_proj<<<dim3(32, 12, 3), 256, 0, stream>>>(Xb, Wb, qb, kb, vtb);
  k_attn<<<dim3(768), 512, 0, stream>>>(qb, kb, vtb, s_v, s_r, attn);
  k_outproj<<<dim3(32, 12), 256, 0, stream>>>(attn, Wb + 3 * 589824, out);
}

// Round 17
// 79.762 us; speedup vs baseline: 1.2966x; 1.0097x over previous
//
#include <hip/hip_runtime.h>
#include <hip/hip_bf16.h>
#include <math.h>

// ScreeningAttention: B=2, T=2048, D_MODEL=768, H=12, D=64
// Round 17 = round-16 (80.5us best) + k_proj/k_outproj re-waved to 512-thread
// blocks (8 waves, 32x32 quadrant per wave) -> 24 waves/CU (was 12), same
// 128x64 tiles, same LDS, same proven dbuf schedule.
// k_cvt -> k_proj (128x64, 8-wave) -> k_attn (8-wave, r16-proven) ->
// k_outproj (128x64, 8-wave).
// LESSONS: v_cvt_pk_bf16_f32 asm pack = correctness bug (r4/6/7). A-direct /
// fused-cvt k_proj = regression (r10 uncoalesced, r12 serial path). k_attn
// strip-tiling = regression (r13: L2 locality loss, FETCH 13->79MB).

typedef __attribute__((ext_vector_type(8))) short short8;     // 8 bf16, MFMA A/B frag
typedef __attribute__((ext_vector_type(4))) float f32x4;      // MFMA C/D frag
typedef __attribute__((ext_vector_type(4))) unsigned int uint4v;
typedef __attribute__((ext_vector_type(2))) unsigned int uint2v;
typedef __attribute__((ext_vector_type(4))) float float4v;

#define MFMA_BF16(a, b, c) __builtin_amdgcn_mfma_f32_16x16x32_bf16((a), (b), (c), 0, 0, 0)

// round-to-nearest-even f32->bf16, bit-manip (round-3-proven).
static __device__ __forceinline__ unsigned short f2bf(float f) {
  union { float f; unsigned u; } v; v.f = f;
  unsigned r = v.u + 0x7FFFu + ((v.u >> 16) & 1u);
  return (unsigned short)(r >> 16);
}
static __device__ __forceinline__ unsigned pack2(float a, float b) {
  return (unsigned)f2bf(a) | ((unsigned)f2bf(b) << 16);
}
// async global->LDS, 16B per lane. LDS dest = wave-uniform base + lane*16.
static __device__ __forceinline__ void gload_lds16(const void* g, void* l) {
  __builtin_amdgcn_global_load_lds((const __attribute__((address_space(1))) unsigned int*)g,
                                   (__attribute__((address_space(3))) unsigned int*)l, 16, 0, 0);
}

// ---------------------------------------------------------------------------
// Kernel 0: convert Xq,Xk,Xv (3x3145728) + Wq,Wk,Wv,Wo (4x589824) f32->bf16
// into one contiguous bf16 region. grid 5760x256, 8 elems/thread.
// ---------------------------------------------------------------------------
__global__ __launch_bounds__(256) void k_cvt(
    const float* __restrict__ s0, const float* __restrict__ s1, const float* __restrict__ s2,
    const float* __restrict__ s3, const float* __restrict__ s4, const float* __restrict__ s5,
    const float* __restrict__ s6, unsigned short* __restrict__ dst) {
  const size_t e = ((size_t)blockIdx.x * 256 + threadIdx.x) * 8;
  const float* src;
  size_t off;
  if (e < 9437184) {
    const int i = (int)(e / 3145728);
    src = (i == 0) ? s0 : (i == 1) ? s1 : s2;
    off = e - (size_t)i * 3145728;
  } else {
    const size_t ew = e - 9437184;
    const int i = (int)(ew / 589824);
    src = (i == 0) ? s3 : (i == 1) ? s4 : (i == 2) ? s5 : s6;
    off = ew - (size_t)i * 589824;
  }
  const float4v f0 = *(const float4v*)(src + off);
  const float4v f1 = *(const float4v*)(src + off + 4);
  uint4v u = {pack2(f0.x, f0.y), pack2(f0.z, f0.w), pack2(f1.x, f1.y), pack2(f1.z, f1.w)};
  *(uint4v*)(dst + e) = u;
}

// ---------------------------------------------------------------------------
// Kernel 1: QKV projection (bf16 inputs) + per-head l2 normalization.
// 128x64 tile (1 head/block), 8 WAVES (512 thr): wave (wm,wn)=(wv>>1,wv&1)
// owns 32-row x 32-col quadrant (ar[2], br[2], acc[2][2]). dbuf schedule +
// XOR chunk-swizzle (proven). which==2 (V) writes TRANSPOSED to vtb.
// LDS: A0@0 (16K), B0@16384 (8K), A1@24576, B1@40960. 48KB -> 3 blocks/CU
// -> 24 waves/CU. grid = (32, 12, 3); block = 512.
// ---------------------------------------------------------------------------
__global__ __launch_bounds__(512) void k_proj(
    const unsigned short* __restrict__ Xb, const unsigned short* __restrict__ Wb,
    unsigned short* __restrict__ qb, unsigned short* __restrict__ kb,
    unsigned short* __restrict__ vtb) {
  __shared__ alignas(16) unsigned char smem[49152];
  float* o_s = (float*)smem;                     // f32[128][68] epilogue alias (34816 B)
  unsigned short* vt_s = (unsigned short*)smem;  // bf16[64][136] V epilogue alias

  const int which = blockIdx.z;
  const int h = blockIdx.y;
  const unsigned short* X = Xb + (size_t)which * 3145728;
  const unsigned short* W = Wb + (size_t)which * 589824 + (size_t)h * 64 * 768;

  const int mbase = blockIdx.x * 128;
  const int tid = threadIdx.x;
  const int lane = tid & 63;
  const int wv = tid >> 6;              // 0..7
  const int wm = wv >> 1, wn = wv & 1;  // 32-row group, 32-col half
  const int l15 = lane & 15, l4 = lane >> 4;
  const int srow8 = lane >> 3;
  const int schunk = (lane & 7) ^ srow8;

  f32x4 acc[2][2];
#pragma unroll
  for (int m = 0; m < 2; ++m)
#pragma unroll
    for (int n = 0; n < 2; ++n) acc[m][n] = (f32x4){0.f, 0.f, 0.f, 0.f};

  // prologue: stage ks=0 into buffer 0 (A: 2/wave, B: 1/wave)
#pragma unroll
  for (int i = 0; i < 2; ++i) {
    const int j = wv * 2 + i;
    gload_lds16(X + (size_t)(mbase + j * 8 + srow8) * 768 + schunk * 8, smem + j * 1024);
  }
  gload_lds16(W + (size_t)(wv * 8 + srow8) * 768 + schunk * 8, smem + 16384 + wv * 1024);

  for (int ks = 0; ks < 12; ++ks) {
    const int cur = (ks & 1) * 24576;
    asm volatile("s_waitcnt vmcnt(0)" ::: "memory");
    __builtin_amdgcn_sched_barrier(0);
    __builtin_amdgcn_s_barrier();
    __builtin_amdgcn_sched_barrier(0);
    if (ks < 11) {
      const int nxt = ((ks + 1) & 1) * 24576;
      const int k0n = (ks + 1) * 64;
#pragma unroll
      for (int i = 0; i < 2; ++i) {
        const int j = wv * 2 + i;
        gload_lds16(X + (size_t)(mbase + j * 8 + srow8) * 768 + k0n + schunk * 8,
                    smem + nxt + j * 1024);
      }
      gload_lds16(W + (size_t)(wv * 8 + srow8) * 768 + k0n + schunk * 8,
                  smem + nxt + 16384 + wv * 1024);
      __builtin_amdgcn_sched_barrier(0);  // pin prefetch issue before compute
    }
    __builtin_amdgcn_s_setprio(1);
#pragma unroll
    for (int kc = 0; kc < 2; ++kc) {
      const int cx = (kc << 2) | l4;
      short8 ar[2], br[2];
#pragma unroll
      for (int m = 0; m < 2; ++m) {
        const int r = wm * 32 + m * 16 + l15;
        ar[m] = *(const short8*)(smem + cur + r * 128 + ((cx ^ (r & 7)) << 4));
      }
#pragma unroll
      for (int n = 0; n < 2; ++n) {
        const int r = wn * 32 + n * 16 + l15;
        br[n] = *(const short8*)(smem + cur + 16384 + r * 128 + ((cx ^ (r & 7)) << 4));
      }
#pragma unroll
      for (int m = 0; m < 2; ++m)
#pragma unroll
        for (int n = 0; n < 2; ++n) acc[m][n] = MFMA_BF16(ar[m], br[n], acc[m][n]);
    }
    __builtin_amdgcn_s_setprio(0);
  }

  // epilogue: single pass (whole 128x64 head tile), 512 threads
  const int b = mbase >> 11;
  const int tbase = mbase & 2047;
  const int bh = b * 12 + h;
  __syncthreads();
#pragma unroll
  for (int m = 0; m < 2; ++m)
#pragma unroll
    for (int n = 0; n < 2; ++n)
#pragma unroll
      for (int j = 0; j < 4; ++j)
        o_s[(wm * 32 + m * 16 + l4 * 4 + j) * 68 + wn * 32 + n * 16 + l15] = acc[m][n][j];
  __syncthreads();
  const int row2 = tid >> 2, q4 = tid & 3;  // 128 rows x 4 threads (16 d each)
  float v[16];
  float ss = 0.f;
#pragma unroll
  for (int c = 0; c < 4; ++c) {
    float4v f = *(const float4v*)(o_s + row2 * 68 + q4 * 16 + c * 4);
    v[c * 4 + 0] = f.x; v[c * 4 + 1] = f.y; v[c * 4 + 2] = f.z; v[c * 4 + 3] = f.w;
    ss += f.x * f.x + f.y * f.y + f.z * f.z + f.w * f.w;
  }
  ss += __shfl_xor(ss, 1);
  ss += __shfl_xor(ss, 2);
  const float inv = 1.f / fmaxf(sqrtf(ss), 1e-8f);
  if (which < 2) {
    unsigned short* outp =
        ((which == 0) ? qb : kb) + ((size_t)bh * 2048 + tbase + row2) * 64 + q4 * 16;
    uint4v o0 = {pack2(v[0] * inv, v[1] * inv), pack2(v[2] * inv, v[3] * inv),
                 pack2(v[4] * inv, v[5] * inv), pack2(v[6] * inv, v[7] * inv)};
    uint4v o1 = {pack2(v[8] * inv, v[9] * inv), pack2(v[10] * inv, v[11] * inv),
                 pack2(v[12] * inv, v[13] * inv), pack2(v[14] * inv, v[15] * inv)};
    *(uint4v*)(outp) = o0;
    *(uint4v*)(outp + 8) = o1;
  } else {
    __syncthreads();  // o_s reads done (v in regs); vt_s aliases o_s
#pragma unroll
    for (int c = 0; c < 16; ++c)
      vt_s[(q4 * 16 + c) * 136 + row2] = f2bf(v[c] * inv);
    __syncthreads();
    const int d = tid >> 3, tc = (tid & 7) * 16;  // 64 d x 8 threads (16 t each)
    unsigned short* dst = vtb + ((size_t)bh * 64 + d) * 2048 + tbase + tc;
    *(uint4v*)(dst) = *(const uint4v*)(vt_s + d * 136 + tc);
    *(uint4v*)(dst + 8) = *(const uint4v*)(vt_s + d * 136 + tc + 8);
  }
}

// ---------------------------------------------------------------------------
// Kernel 2: causal screening attention, 8-WAVE blocks (512 threads)
// (ROUND-16 PASSING, unchanged).
// LDS: K0 @0, K1 @8192, V0 @16384, V1 @24576, p_s @32768 (9216). 41984 B.
// grid = 768; block = 512.
// ---------------------------------------------------------------------------
__global__ __launch_bounds__(512) void k_attn(
    const unsigned short* __restrict__ qb, const unsigned short* __restrict__ kb,
    const unsigned short* __restrict__ vtb, const float* __restrict__ s_v,
    const float* __restrict__ s_r, unsigned short* __restrict__ attn) {
  __shared__ alignas(16) unsigned char smem[41984];
  unsigned short* p_s = (unsigned short*)(smem + 32768);  // [64 q][72 key] bf16
  float* o_s = (float*)smem;                              // [64][68] f32 epilogue alias

  const int bid = blockIdx.x;
  const int ii = bid & 255, jj = bid >> 8;
  const int rank = (jj == 0) ? ii : (jj == 1) ? (511 - ii) : (512 + ii);
  const int qt = 31 - (rank / 24);  // heavy tasks at low rank
  const int bh = rank % 24;
  const int b = bh / 12, h = bh % 12;
  const int qbase = qt * 64;
  const unsigned short* Qp = qb + (size_t)bh * 2048 * 64;
  const unsigned short* Kp = kb + (size_t)bh * 2048 * 64;
  const unsigned short* VTp = vtb + (size_t)bh * 64 * 2048;

  const int tid = threadIdx.x;
  const int lane = tid & 63;
  const int wv = tid >> 6;              // 0..7
  const int wm = wv >> 2, wn = wv & 3;  // S: wm=key-half, wn=q-quarter. PV: wm=d-half.
  const int l15 = lane & 15, l4 = lane >> 4;
  const int srow8 = lane >> 3;
  const int schunk = (lane & 7) ^ srow8;

  const float w_h = expf(s_v[h]) + 1.0f;          // decay exponent, [2,256]
  const float lr_h = log2f(expf(s_r[h]) + 1.0f);  // log2 of per-head scale

  // prologue: issue kt=0 K/V gloads, 1 instr/wave each (8 waves x 8 rows)
  gload_lds16(Kp + (size_t)(wv * 8 + srow8) * 64 + schunk * 8, smem + wv * 1024);
  gload_lds16(VTp + (size_t)(wv * 8 + srow8) * 2048 + schunk * 8, smem + 16384 + wv * 1024);

  // hoist Q fragments (B-operand of swapped S) straight from global
  short8 qf[2];
#pragma unroll
  for (int kc = 0; kc < 2; ++kc)
    qf[kc] = *(const short8*)(Qp + (size_t)(qbase + wn * 16 + l15) * 64 + kc * 32 + l4 * 8);

  f32x4 acc_o[2];  // [d-half within wave's 32-wide d group]
#pragma unroll
  for (int m = 0; m < 2; ++m) acc_o[m] = (f32x4){0.f, 0.f, 0.f, 0.f};

  for (int kt = 0; kt <= qt; ++kt) {
    const int cur = (kt & 1) * 8192;
    asm volatile("s_waitcnt vmcnt(0)" ::: "memory");
    __builtin_amdgcn_sched_barrier(0);
    __builtin_amdgcn_s_barrier();
    __builtin_amdgcn_sched_barrier(0);
    if (kt < qt) {
      const int nxt = ((kt + 1) & 1) * 8192;
      const int kb2 = (kt + 1) * 64;
      gload_lds16(Kp + (size_t)(kb2 + wv * 8 + srow8) * 64 + schunk * 8, smem + nxt + wv * 1024);
      gload_lds16(VTp + (size_t)(wv * 8 + srow8) * 2048 + kb2 + schunk * 8,
                  smem + 16384 + nxt + wv * 1024);
      __builtin_amdgcn_sched_barrier(0);  // pin prefetch issue before compute
    }
    // S^T = K Q^T : rows = keys (wave's 32-key half), cols = q (wave's 16-q)
    f32x4 s_acc[2];
#pragma unroll
    for (int m = 0; m < 2; ++m) s_acc[m] = (f32x4){0.f, 0.f, 0.f, 0.f};
    __builtin_amdgcn_s_setprio(1);
#pragma unroll
    for (int kc = 0; kc < 2; ++kc) {
      const int cx = (kc << 2) | l4;
      const int r0 = wm * 32 + l15, r1 = wm * 32 + 16 + l15;
      short8 a0 = *(const short8*)(smem + cur + r0 * 128 + ((cx ^ (r0 & 7)) << 4));
      short8 a1 = *(const short8*)(smem + cur + r1 * 128 + ((cx ^ (r1 & 7)) << 4));
      s_acc[0] = MFMA_BF16(a0, qf[kc], s_acc[0]);
      s_acc[1] = MFMA_BF16(a1, qf[kc], s_acc[1]);
    }
    __builtin_amdgcn_s_setprio(0);
    // alpha = r * clamp((s+1)/2)^w
    const bool diag = (kt == qt);
#pragma unroll
    for (int m = 0; m < 2; ++m) {
      const int lkb = wm * 32 + m * 16 + l4 * 4;  // key base (reg dim)
      const int lq = wn * 16 + l15;               // q (lane dim)
      float av[4];
#pragma unroll
      for (int t = 0; t < 4; ++t) {
        const float base = __builtin_amdgcn_fmed3f(fmaf(s_acc[m][t], 0.5f, 0.5f), 0.f, 1.f);
        float a = __builtin_amdgcn_exp2f(fmaf(w_h, __builtin_amdgcn_logf(base), lr_h));
        if (diag && (lkb + t) > lq) a = 0.f;
        av[t] = a;
      }
      uint2v u = {pack2(av[0], av[1]), pack2(av[2], av[3])};
      *(uint2v*)(p_s + lq * 72 + lkb) = u;
    }
    asm volatile("s_waitcnt lgkmcnt(0)" ::: "memory");
    __builtin_amdgcn_sched_barrier(0);
    __builtin_amdgcn_s_barrier();
    __builtin_amdgcn_sched_barrier(0);
    // O += P V
    __builtin_amdgcn_s_setprio(1);
#pragma unroll
    for (int kc = 0; kc < 2; ++kc) {
      const int cx = (kc << 2) | l4;
      const int r0 = wm * 32 + l15, r1 = wm * 32 + 16 + l15;
      short8 pa = *(const short8*)(p_s + (wn * 16 + l15) * 72 + kc * 32 + l4 * 8);
      short8 vb0 = *(const short8*)(smem + 16384 + cur + r0 * 128 + ((cx ^ (r0 & 7)) << 4));
      short8 vb1 = *(const short8*)(smem + 16384 + cur + r1 * 128 + ((cx ^ (r1 & 7)) << 4));
      acc_o[0] = MFMA_BF16(pa, vb0, acc_o[0]);
      acc_o[1] = MFMA_BF16(pa, vb1, acc_o[1]);
    }
    __builtin_amdgcn_s_setprio(0);
  }
  __syncthreads();
#pragma unroll
  for (int m = 0; m < 2; ++m)
#pragma unroll
    for (int j = 0; j < 4; ++j)
      o_s[(wn * 16 + l4 * 4 + j) * 68 + wm * 32 + m * 16 + l15] = acc_o[m][j];
  __syncthreads();
  // TanhNorm: out = tanh(n) * out / (n + eps). 8 threads/row x 8 d each.
  {
    const int row = tid >> 3, d8 = (tid & 7) * 8;
    float vals[8];
    float ss = 0.f;
#pragma unroll
    for (int c = 0; c < 2; ++c) {
      float4v f = *(const float4v*)(o_s + row * 68 + d8 + c * 4);
      vals[c * 4 + 0] = f.x; vals[c * 4 + 1] = f.y; vals[c * 4 + 2] = f.z; vals[c * 4 + 3] = f.w;
      ss += f.x * f.x + f.y * f.y + f.z * f.z + f.w * f.w;
    }
    ss += __shfl_xor(ss, 1);
    ss += __shfl_xor(ss, 2);
    ss += __shfl_xor(ss, 4);
    const float nrm = sqrtf(ss);
    const float sc = tanhf(nrm) / (nrm + 1e-8f);
    unsigned short* dst = attn + (size_t)(b * 2048 + qbase + row) * 768 + h * 64 + d8;
    uint4v o = {pack2(vals[0] * sc, vals[1] * sc), pack2(vals[2] * sc, vals[3] * sc),
                pack2(vals[4] * sc, vals[5] * sc), pack2(vals[6] * sc, vals[7] * sc)};
    *(uint4v*)(dst) = o;
  }
}

// ---------------------------------------------------------------------------
// Kernel 3: out = attn[4096x768](bf16) @ Wo^T(bf16) -> f32. 128x64 tile,
// 8 WAVES (512 thr): wave (wm,wn)=(wv>>1,wv&1) owns 32x32 quadrant.
// Same dbuf schedule. LDS: A0@0 (16K), B0@16384 (8K), A1@24576, B1@40960.
// grid (32,12); block = 512.
// ---------------------------------------------------------------------------
__global__ __launch_bounds__(512) void k_outproj(const unsigned short* __restrict__ attn,
                                                 const unsigned short* __restrict__ Wob,
                                                 float* __restrict__ out) {
  __shared__ alignas(16) unsigned char smem[49152];
  const int mbase = blockIdx.x * 128;
  const int nbase = blockIdx.y * 64;
  const int tid = threadIdx.x;
  const int lane = tid & 63;
  const int wv = tid >> 6;
  const int wm = wv >> 1, wn = wv & 1;
  const int l15 = lane & 15, l4 = lane >> 4;
  const int srow8 = lane >> 3;
  const int schunk = (lane & 7) ^ srow8;

  f32x4 acc[2][2];
#pragma unroll
  for (int m = 0; m < 2; ++m)
#pragma unroll
    for (int n = 0; n < 2; ++n) acc[m][n] = (f32x4){0.f, 0.f, 0.f, 0.f};

  // prologue: stage ks=0 into buffer 0 (A: 2/wave, B: 1/wave)
#pragma unroll
  for (int i = 0; i < 2; ++i) {
    const int j = wv * 2 + i;
    gload_lds16(attn + (size_t)(mbase + j * 8 + srow8) * 768 + schunk * 8, smem + j * 1024);
  }
  gload_lds16(Wob + (size_t)(nbase + wv * 8 + srow8) * 768 + schunk * 8,
              smem + 16384 + wv * 1024);

  for (int ks = 0; ks < 12; ++ks) {
    const int cur = (ks & 1) * 24576;
    asm volatile("s_waitcnt vmcnt(0)" ::: "memory");
    __builtin_amdgcn_sched_barrier(0);
    __builtin_amdgcn_s_barrier();
    __builtin_amdgcn_sched_barrier(0);
    if (ks < 11) {
      const int nxt = ((ks + 1) & 1) * 24576;
      const int k0n = (ks + 1) * 64;
#pragma unroll
      for (int i = 0; i < 2; ++i) {
        const int j = wv * 2 + i;
        gload_lds16(attn + (size_t)(mbase + j * 8 + srow8) * 768 + k0n + schunk * 8,
                    smem + nxt + j * 1024);
      }
      gload_lds16(Wob + (size_t)(nbase + wv * 8 + srow8) * 768 + k0n + schunk * 8,
                  smem + nxt + 16384 + wv * 1024);
      __builtin_amdgcn_sched_barrier(0);
    }
    __builtin_amdgcn_s_setprio(1);
#pragma unroll
    for (int kc = 0; kc < 2; ++kc) {
      const int cx = (kc << 2) | l4;
      short8 ar[2], br[2];
#pragma unroll
      for (int m = 0; m < 2; ++m) {
        const int r = wm * 32 + m * 16 + l15;
        ar[m] = *(const short8*)(smem + cur + r * 128 + ((cx ^ (r & 7)) << 4));
      }
#pragma unroll
      for (int n = 0; n < 2; ++n) {
        const int r = wn * 32 + n * 16 + l15;
        br[n] = *(const short8*)(smem + cur + 16384 + r * 128 + ((cx ^ (r & 7)) << 4));
      }
#pragma unroll
      for (int m = 0; m < 2; ++m)
#pragma unroll
        for (int n = 0; n < 2; ++n) acc[m][n] = MFMA_BF16(ar[m], br[n], acc[m][n]);
    }
    __builtin_amdgcn_s_setprio(0);
  }
#pragma unroll
  for (int m = 0; m < 2; ++m)
#pragma unroll
    for (int n = 0; n < 2; ++n)
#pragma unroll
      for (int j = 0; j < 4; ++j)
        out[(size_t)(mbase + wm * 32 + m * 16 + l4 * 4 + j) * 768 + nbase + wn * 32 + n * 16 +
            l15] = acc[m][n][j];
}

extern "C" void kernel_launch(void* const* d_in, const int* in_sizes, int n_in, void* d_out,
                              int out_size, void* d_ws, size_t ws_size, hipStream_t stream) {
  (void)in_sizes;
  (void)n_in;
  (void)out_size;
  (void)ws_size;
  const float* query = (const float*)d_in[0];
  const float* key = (const float*)d_in[1];
  const float* value = (const float*)d_in[2];
  const float* Wq = (const float*)d_in[3];
  const float* Wk = (const float*)d_in[4];
  const float* Wv = (const float*)d_in[5];
  const float* Wo = (const float*)d_in[6];
  const float* s_v = (const float*)d_in[7];
  const float* s_r = (const float*)d_in[8];
  float* out = (float*)d_out;

  // ws layout (bf16 elems): [Xb 3x3145728 | Wb 4x589824 | qb | kb | vtb]
  // attn aliases Xb (dead after k_proj). Total 42.5 MB.
  unsigned short* cvt = (unsigned short*)d_ws;
  unsigned short* Xb = cvt;
  unsigned short* Wb = cvt + 9437184;
  unsigned short* qb = cvt + 11796480;
  unsigned short* kb = qb + 3145728;
  unsigned short* vtb = kb + 3145728;
  unsigned short* attn = cvt;

  k_cvt<<<5760, 256, 0, stream>>>(query, key, value, Wq, Wk, Wv, Wo, cvt);
  k_proj<<<dim3(32, 12, 3), 512, 0, stream>>>(Xb, Wb, qb, kb, vtb);
  k_attn<<<dim3(768), 512, 0, stream>>>(qb, kb, vtb, s_v, s_r, attn);
  k_outproj<<<dim3(32, 12), 512, 0, stream>>>(attn, Wb + 3 * 589824, out);
}

// Round 18
// 77.168 us; speedup vs baseline: 1.3402x; 1.0336x over previous
//
#include <hip/hip_runtime.h>
#include <hip/hip_bf16.h>
#include <math.h>

// ScreeningAttention: B=2, T=2048, D_MODEL=768, H=12, D=64
// Round 18 = round-17 (79.8us best) + k_attn PV restructured wave-private:
// O^T[d][q] += mfma(A=V^T[d][key-half], B=P[key-half][q]) with each wave
// reducing ONLY its own 32-key half (K=32) -> p_s write/read is wave-private
// -> the per-tile p_s barrier is deleted (lgkmcnt-only). wm partial-O halves
// summed once in the epilogue. One barrier per key-tile instead of two.
// k_cvt -> k_proj (128x64, 8-wave) -> k_attn (8-wave, 1-barrier tiles) ->
// k_outproj (128x64, 8-wave).
// LESSONS: v_cvt_pk_bf16_f32 asm pack = correctness bug (r4/6/7). A-direct /
// fused-cvt k_proj = regression (r10 uncoalesced, r12 serial path). k_attn
// strip-tiling = regression (r13: L2 locality loss).

typedef __attribute__((ext_vector_type(8))) short short8;     // 8 bf16, MFMA A/B frag
typedef __attribute__((ext_vector_type(4))) float f32x4;      // MFMA C/D frag
typedef __attribute__((ext_vector_type(4))) unsigned int uint4v;
typedef __attribute__((ext_vector_type(2))) unsigned int uint2v;
typedef __attribute__((ext_vector_type(4))) float float4v;

#define MFMA_BF16(a, b, c) __builtin_amdgcn_mfma_f32_16x16x32_bf16((a), (b), (c), 0, 0, 0)

// round-to-nearest-even f32->bf16, bit-manip (round-3-proven).
static __device__ __forceinline__ unsigned short f2bf(float f) {
  union { float f; unsigned u; } v; v.f = f;
  unsigned r = v.u + 0x7FFFu + ((v.u >> 16) & 1u);
  return (unsigned short)(r >> 16);
}
static __device__ __forceinline__ unsigned pack2(float a, float b) {
  return (unsigned)f2bf(a) | ((unsigned)f2bf(b) << 16);
}
// async global->LDS, 16B per lane. LDS dest = wave-uniform base + lane*16.
static __device__ __forceinline__ void gload_lds16(const void* g, void* l) {
  __builtin_amdgcn_global_load_lds((const __attribute__((address_space(1))) unsigned int*)g,
                                   (__attribute__((address_space(3))) unsigned int*)l, 16, 0, 0);
}

// ---------------------------------------------------------------------------
// Kernel 0: convert Xq,Xk,Xv (3x3145728) + Wq,Wk,Wv,Wo (4x589824) f32->bf16
// into one contiguous bf16 region. grid 5760x256, 8 elems/thread.
// ---------------------------------------------------------------------------
__global__ __launch_bounds__(256) void k_cvt(
    const float* __restrict__ s0, const float* __restrict__ s1, const float* __restrict__ s2,
    const float* __restrict__ s3, const float* __restrict__ s4, const float* __restrict__ s5,
    const float* __restrict__ s6, unsigned short* __restrict__ dst) {
  const size_t e = ((size_t)blockIdx.x * 256 + threadIdx.x) * 8;
  const float* src;
  size_t off;
  if (e < 9437184) {
    const int i = (int)(e / 3145728);
    src = (i == 0) ? s0 : (i == 1) ? s1 : s2;
    off = e - (size_t)i * 3145728;
  } else {
    const size_t ew = e - 9437184;
    const int i = (int)(ew / 589824);
    src = (i == 0) ? s3 : (i == 1) ? s4 : (i == 2) ? s5 : s6;
    off = ew - (size_t)i * 589824;
  }
  const float4v f0 = *(const float4v*)(src + off);
  const float4v f1 = *(const float4v*)(src + off + 4);
  uint4v u = {pack2(f0.x, f0.y), pack2(f0.z, f0.w), pack2(f1.x, f1.y), pack2(f1.z, f1.w)};
  *(uint4v*)(dst + e) = u;
}

// ---------------------------------------------------------------------------
// Kernel 1: QKV projection (bf16 inputs) + per-head l2 normalization.
// 128x64 tile (1 head/block), 8 WAVES (512 thr), dbuf schedule (r17-proven).
// which==2 (V) writes TRANSPOSED to vtb [bh][d][t].
// LDS: A0@0 (16K), B0@16384 (8K), A1@24576, B1@40960. 48KB -> 3 blocks/CU.
// grid = (32, 12, 3); block = 512.
// ---------------------------------------------------------------------------
__global__ __launch_bounds__(512) void k_proj(
    const unsigned short* __restrict__ Xb, const unsigned short* __restrict__ Wb,
    unsigned short* __restrict__ qb, unsigned short* __restrict__ kb,
    unsigned short* __restrict__ vtb) {
  __shared__ alignas(16) unsigned char smem[49152];
  float* o_s = (float*)smem;                     // f32[128][68] epilogue alias (34816 B)
  unsigned short* vt_s = (unsigned short*)smem;  // bf16[64][136] V epilogue alias

  const int which = blockIdx.z;
  const int h = blockIdx.y;
  const unsigned short* X = Xb + (size_t)which * 3145728;
  const unsigned short* W = Wb + (size_t)which * 589824 + (size_t)h * 64 * 768;

  const int mbase = blockIdx.x * 128;
  const int tid = threadIdx.x;
  const int lane = tid & 63;
  const int wv = tid >> 6;              // 0..7
  const int wm = wv >> 1, wn = wv & 1;  // 32-row group, 32-col half
  const int l15 = lane & 15, l4 = lane >> 4;
  const int srow8 = lane >> 3;
  const int schunk = (lane & 7) ^ srow8;

  f32x4 acc[2][2];
#pragma unroll
  for (int m = 0; m < 2; ++m)
#pragma unroll
    for (int n = 0; n < 2; ++n) acc[m][n] = (f32x4){0.f, 0.f, 0.f, 0.f};

  // prologue: stage ks=0 into buffer 0 (A: 2/wave, B: 1/wave)
#pragma unroll
  for (int i = 0; i < 2; ++i) {
    const int j = wv * 2 + i;
    gload_lds16(X + (size_t)(mbase + j * 8 + srow8) * 768 + schunk * 8, smem + j * 1024);
  }
  gload_lds16(W + (size_t)(wv * 8 + srow8) * 768 + schunk * 8, smem + 16384 + wv * 1024);

  for (int ks = 0; ks < 12; ++ks) {
    const int cur = (ks & 1) * 24576;
    asm volatile("s_waitcnt vmcnt(0)" ::: "memory");
    __builtin_amdgcn_sched_barrier(0);
    __builtin_amdgcn_s_barrier();
    __builtin_amdgcn_sched_barrier(0);
    if (ks < 11) {
      const int nxt = ((ks + 1) & 1) * 24576;
      const int k0n = (ks + 1) * 64;
#pragma unroll
      for (int i = 0; i < 2; ++i) {
        const int j = wv * 2 + i;
        gload_lds16(X + (size_t)(mbase + j * 8 + srow8) * 768 + k0n + schunk * 8,
                    smem + nxt + j * 1024);
      }
      gload_lds16(W + (size_t)(wv * 8 + srow8) * 768 + k0n + schunk * 8,
                  smem + nxt + 16384 + wv * 1024);
      __builtin_amdgcn_sched_barrier(0);  // pin prefetch issue before compute
    }
    __builtin_amdgcn_s_setprio(1);
#pragma unroll
    for (int kc = 0; kc < 2; ++kc) {
      const int cx = (kc << 2) | l4;
      short8 ar[2], br[2];
#pragma unroll
      for (int m = 0; m < 2; ++m) {
        const int r = wm * 32 + m * 16 + l15;
        ar[m] = *(const short8*)(smem + cur + r * 128 + ((cx ^ (r & 7)) << 4));
      }
#pragma unroll
      for (int n = 0; n < 2; ++n) {
        const int r = wn * 32 + n * 16 + l15;
        br[n] = *(const short8*)(smem + cur + 16384 + r * 128 + ((cx ^ (r & 7)) << 4));
      }
#pragma unroll
      for (int m = 0; m < 2; ++m)
#pragma unroll
        for (int n = 0; n < 2; ++n) acc[m][n] = MFMA_BF16(ar[m], br[n], acc[m][n]);
    }
    __builtin_amdgcn_s_setprio(0);
  }

  // epilogue: single pass (whole 128x64 head tile), 512 threads
  const int b = mbase >> 11;
  const int tbase = mbase & 2047;
  const int bh = b * 12 + h;
  __syncthreads();
#pragma unroll
  for (int m = 0; m < 2; ++m)
#pragma unroll
    for (int n = 0; n < 2; ++n)
#pragma unroll
      for (int j = 0; j < 4; ++j)
        o_s[(wm * 32 + m * 16 + l4 * 4 + j) * 68 + wn * 32 + n * 16 + l15] = acc[m][n][j];
  __syncthreads();
  const int row2 = tid >> 2, q4 = tid & 3;  // 128 rows x 4 threads (16 d each)
  float v[16];
  float ss = 0.f;
#pragma unroll
  for (int c = 0; c < 4; ++c) {
    float4v f = *(const float4v*)(o_s + row2 * 68 + q4 * 16 + c * 4);
    v[c * 4 + 0] = f.x; v[c * 4 + 1] = f.y; v[c * 4 + 2] = f.z; v[c * 4 + 3] = f.w;
    ss += f.x * f.x + f.y * f.y + f.z * f.z + f.w * f.w;
  }
  ss += __shfl_xor(ss, 1);
  ss += __shfl_xor(ss, 2);
  const float inv = 1.f / fmaxf(sqrtf(ss), 1e-8f);
  if (which < 2) {
    unsigned short* outp =
        ((which == 0) ? qb : kb) + ((size_t)bh * 2048 + tbase + row2) * 64 + q4 * 16;
    uint4v o0 = {pack2(v[0] * inv, v[1] * inv), pack2(v[2] * inv, v[3] * inv),
                 pack2(v[4] * inv, v[5] * inv), pack2(v[6] * inv, v[7] * inv)};
    uint4v o1 = {pack2(v[8] * inv, v[9] * inv), pack2(v[10] * inv, v[11] * inv),
                 pack2(v[12] * inv, v[13] * inv), pack2(v[14] * inv, v[15] * inv)};
    *(uint4v*)(outp) = o0;
    *(uint4v*)(outp + 8) = o1;
  } else {
    __syncthreads();  // o_s reads done (v in regs); vt_s aliases o_s
#pragma unroll
    for (int c = 0; c < 16; ++c)
      vt_s[(q4 * 16 + c) * 136 + row2] = f2bf(v[c] * inv);
    __syncthreads();
    const int d = tid >> 3, tc = (tid & 7) * 16;  // 64 d x 8 threads (16 t each)
    unsigned short* dst = vtb + ((size_t)bh * 64 + d) * 2048 + tbase + tc;
    *(uint4v*)(dst) = *(const uint4v*)(vt_s + d * 136 + tc);
    *(uint4v*)(dst + 8) = *(const uint4v*)(vt_s + d * 136 + tc + 8);
  }
}

// ---------------------------------------------------------------------------
// Kernel 2: causal screening attention, 8-WAVE blocks, ONE barrier per tile.
// Wave (wm,wn)=(wv>>2,wv&3): key/d... S: rows=keys wm*32+{0,16}, cols=q
// wn*16 (unchanged). PV swapped: O^T[d][q] += mfma(A=V^T[d][keys wm-half],
// B=P[keys wm-half][q]) -- K=32, 4 d-groups, p_s region WAVE-PRIVATE
// (rows q=wn*16.., cols wm*32..) so only lgkmcnt(0) between write and read.
// wm=0/1 partial-O halves summed once in epilogue via o_s.
// LDS: K0 @0, K1 @8192, V0 @16384, V1 @24576, p_s @32768 (9216). 41984 B.
// grid = 768; block = 512.
// ---------------------------------------------------------------------------
__global__ __launch_bounds__(512) void k_attn(
    const unsigned short* __restrict__ qb, const unsigned short* __restrict__ kb,
    const unsigned short* __restrict__ vtb, const float* __restrict__ s_v,
    const float* __restrict__ s_r, unsigned short* __restrict__ attn) {
  __shared__ alignas(16) unsigned char smem[41984];
  unsigned short* p_s = (unsigned short*)(smem + 32768);  // [64 q][72 key] bf16
  float* o_s = (float*)smem;                              // [64][68] f32 epilogue alias

  const int bid = blockIdx.x;
  const int ii = bid & 255, jj = bid >> 8;
  const int rank = (jj == 0) ? ii : (jj == 1) ? (511 - ii) : (512 + ii);
  const int qt = 31 - (rank / 24);  // heavy tasks at low rank
  const int bh = rank % 24;
  const int b = bh / 12, h = bh % 12;
  const int qbase = qt * 64;
  const unsigned short* Qp = qb + (size_t)bh * 2048 * 64;
  const unsigned short* Kp = kb + (size_t)bh * 2048 * 64;
  const unsigned short* VTp = vtb + (size_t)bh * 64 * 2048;

  const int tid = threadIdx.x;
  const int lane = tid & 63;
  const int wv = tid >> 6;              // 0..7
  const int wm = wv >> 2, wn = wv & 3;  // wm=key-half, wn=q-quarter
  const int l15 = lane & 15, l4 = lane >> 4;
  const int srow8 = lane >> 3;
  const int schunk = (lane & 7) ^ srow8;

  const float w_h = expf(s_v[h]) + 1.0f;          // decay exponent, [2,256]
  const float lr_h = log2f(expf(s_r[h]) + 1.0f);  // log2 of per-head scale

  // prologue: issue kt=0 K/V gloads, 1 instr/wave each (8 waves x 8 rows)
  gload_lds16(Kp + (size_t)(wv * 8 + srow8) * 64 + schunk * 8, smem + wv * 1024);
  gload_lds16(VTp + (size_t)(wv * 8 + srow8) * 2048 + schunk * 8, smem + 16384 + wv * 1024);

  // hoist Q fragments (B-operand of swapped S) straight from global
  short8 qf[2];
#pragma unroll
  for (int kc = 0; kc < 2; ++kc)
    qf[kc] = *(const short8*)(Qp + (size_t)(qbase + wn * 16 + l15) * 64 + kc * 32 + l4 * 8);

  // partial O^T over this wave's 32-key half: acc_oT[dg] has
  // d = dg*16 + l4*4 + j (row), q = wn*16 + l15 (col/lane).
  f32x4 acc_oT[4];
#pragma unroll
  for (int g = 0; g < 4; ++g) acc_oT[g] = (f32x4){0.f, 0.f, 0.f, 0.f};

  for (int kt = 0; kt <= qt; ++kt) {
    const int cur = (kt & 1) * 8192;
    asm volatile("s_waitcnt vmcnt(0)" ::: "memory");
    __builtin_amdgcn_sched_barrier(0);
    __builtin_amdgcn_s_barrier();
    __builtin_amdgcn_sched_barrier(0);
    if (kt < qt) {
      const int nxt = ((kt + 1) & 1) * 8192;
      const int kb2 = (kt + 1) * 64;
      gload_lds16(Kp + (size_t)(kb2 + wv * 8 + srow8) * 64 + schunk * 8, smem + nxt + wv * 1024);
      gload_lds16(VTp + (size_t)(wv * 8 + srow8) * 2048 + kb2 + schunk * 8,
                  smem + 16384 + nxt + wv * 1024);
      __builtin_amdgcn_sched_barrier(0);  // pin prefetch issue before compute
    }
    // S^T = K Q^T : rows = keys (wave's 32-key half), cols = q (wave's 16-q)
    f32x4 s_acc[2];
#pragma unroll
    for (int m = 0; m < 2; ++m) s_acc[m] = (f32x4){0.f, 0.f, 0.f, 0.f};
    __builtin_amdgcn_s_setprio(1);
#pragma unroll
    for (int kc = 0; kc < 2; ++kc) {
      const int cx = (kc << 2) | l4;
      const int r0 = wm * 32 + l15, r1 = wm * 32 + 16 + l15;
      short8 a0 = *(const short8*)(smem + cur + r0 * 128 + ((cx ^ (r0 & 7)) << 4));
      short8 a1 = *(const short8*)(smem + cur + r1 * 128 + ((cx ^ (r1 & 7)) << 4));
      s_acc[0] = MFMA_BF16(a0, qf[kc], s_acc[0]);
      s_acc[1] = MFMA_BF16(a1, qf[kc], s_acc[1]);
    }
    __builtin_amdgcn_s_setprio(0);
    // alpha = r * clamp((s+1)/2)^w -> wave-private p_s quadrant
    const bool diag = (kt == qt);
#pragma unroll
    for (int m = 0; m < 2; ++m) {
      const int lkb = wm * 32 + m * 16 + l4 * 4;  // key base (reg dim)
      const int lq = wn * 16 + l15;               // q (lane dim)
      float av[4];
#pragma unroll
      for (int t = 0; t < 4; ++t) {
        const float base = __builtin_amdgcn_fmed3f(fmaf(s_acc[m][t], 0.5f, 0.5f), 0.f, 1.f);
        float a = __builtin_amdgcn_exp2f(fmaf(w_h, __builtin_amdgcn_logf(base), lr_h));
        if (diag && (lkb + t) > lq) a = 0.f;
        av[t] = a;
      }
      uint2v u = {pack2(av[0], av[1]), pack2(av[2], av[3])};
      *(uint2v*)(p_s + lq * 72 + lkb) = u;
    }
    // wave-private RAW through LDS: wait writes, no block barrier needed
    asm volatile("s_waitcnt lgkmcnt(0)" ::: "memory");
    __builtin_amdgcn_sched_barrier(0);
    // O^T += V^T * P over this wave's 32 keys (K=32), all 64 d (4 groups).
    // A frag: row d = dg*16+l15, k(keys) = wm*32 + l4*8..+7 (chunk wm*4+l4).
    // B frag: col q = wn*16+l15 (own p_s rows), k = wm*32 + l4*8..+7.
    __builtin_amdgcn_s_setprio(1);
    {
      short8 pb = *(const short8*)(p_s + (wn * 16 + l15) * 72 + wm * 32 + l4 * 8);
#pragma unroll
      for (int dg = 0; dg < 4; ++dg) {
        const int rd = dg * 16 + l15;
        short8 va = *(const short8*)(smem + 16384 + cur + rd * 128 +
                                     (((wm * 4 + l4) ^ (rd & 7)) << 4));
        acc_oT[dg] = MFMA_BF16(va, pb, acc_oT[dg]);
      }
    }
    __builtin_amdgcn_s_setprio(0);
  }
  // cross-wave reduce: wm=0 writes, wm=1 adds; then TanhNorm.
  __syncthreads();
  if (wm == 0) {
#pragma unroll
    for (int dg = 0; dg < 4; ++dg)
#pragma unroll
      for (int j = 0; j < 4; ++j)
        o_s[(wn * 16 + l15) * 68 + dg * 16 + l4 * 4 + j] = acc_oT[dg][j];
  }
  __syncthreads();
  if (wm == 1) {
#pragma unroll
    for (int dg = 0; dg < 4; ++dg)
#pragma unroll
      for (int j = 0; j < 4; ++j)
        o_s[(wn * 16 + l15) * 68 + dg * 16 + l4 * 4 + j] += acc_oT[dg][j];
  }
  __syncthreads();
  // TanhNorm: out = tanh(n) * out / (n + eps). 8 threads/row x 8 d each.
  {
    const int row = tid >> 3, d8 = (tid & 7) * 8;
    float vals[8];
    float ss = 0.f;
#pragma unroll
    for (int c = 0; c < 2; ++c) {
      float4v f = *(const float4v*)(o_s + row * 68 + d8 + c * 4);
      vals[c * 4 + 0] = f.x; vals[c * 4 + 1] = f.y; vals[c * 4 + 2] = f.z; vals[c * 4 + 3] = f.w;
      ss += f.x * f.x + f.y * f.y + f.z * f.z + f.w * f.w;
    }
    ss += __shfl_xor(ss, 1);
    ss += __shfl_xor(ss, 2);
    ss += __shfl_xor(ss, 4);
    const float nrm = sqrtf(ss);
    const float sc = tanhf(nrm) / (nrm + 1e-8f);
    unsigned short* dst = attn + (size_t)(b * 2048 + qbase + row) * 768 + h * 64 + d8;
    uint4v o = {pack2(vals[0] * sc, vals[1] * sc), pack2(vals[2] * sc, vals[3] * sc),
                pack2(vals[4] * sc, vals[5] * sc), pack2(vals[6] * sc, vals[7] * sc)};
    *(uint4v*)(dst) = o;
  }
}

// ---------------------------------------------------------------------------
// Kernel 3: out = attn[4096x768](bf16) @ Wo^T(bf16) -> f32. 128x64 tile,
// 8 WAVES (512 thr, r17-proven). LDS: A0@0, B0@16384, A1@24576, B1@40960.
// grid (32,12); block = 512.
// ---------------------------------------------------------------------------
__global__ __launch_bounds__(512) void k_outproj(const unsigned short* __restrict__ attn,
                                                 const unsigned short* __restrict__ Wob,
                                                 float* __restrict__ out) {
  __shared__ alignas(16) unsigned char smem[49152];
  const int mbase = blockIdx.x * 128;
  const int nbase = blockIdx.y * 64;
  const int tid = threadIdx.x;
  const int lane = tid & 63;
  const int wv = tid >> 6;
  const int wm = wv >> 1, wn = wv & 1;
  const int l15 = lane & 15, l4 = lane >> 4;
  const int srow8 = lane >> 3;
  const int schunk = (lane & 7) ^ srow8;

  f32x4 acc[2][2];
#pragma unroll
  for (int m = 0; m < 2; ++m)
#pragma unroll
    for (int n = 0; n < 2; ++n) acc[m][n] = (f32x4){0.f, 0.f, 0.f, 0.f};

  // prologue: stage ks=0 into buffer 0 (A: 2/wave, B: 1/wave)
#pragma unroll
  for (int i = 0; i < 2; ++i) {
    const int j = wv * 2 + i;
    gload_lds16(attn + (size_t)(mbase + j * 8 + srow8) * 768 + schunk * 8, smem + j * 1024);
  }
  gload_lds16(Wob + (size_t)(nbase + wv * 8 + srow8) * 768 + schunk * 8,
              smem + 16384 + wv * 1024);

  for (int ks = 0; ks < 12; ++ks) {
    const int cur = (ks & 1) * 24576;
    asm volatile("s_waitcnt vmcnt(0)" ::: "memory");
    __builtin_amdgcn_sched_barrier(0);
    __builtin_amdgcn_s_barrier();
    __builtin_amdgcn_sched_barrier(0);
    if (ks < 11) {
      const int nxt = ((ks + 1) & 1) * 24576;
      const int k0n = (ks + 1) * 64;
#pragma unroll
      for (int i = 0; i < 2; ++i) {
        const int j = wv * 2 + i;
        gload_lds16(attn + (size_t)(mbase + j * 8 + srow8) * 768 + k0n + schunk * 8,
                    smem + nxt + j * 1024);
      }
      gload_lds16(Wob + (size_t)(nbase + wv * 8 + srow8) * 768 + k0n + schunk * 8,
                  smem + nxt + 16384 + wv * 1024);
      __builtin_amdgcn_sched_barrier(0);
    }
    __builtin_amdgcn_s_setprio(1);
#pragma unroll
    for (int kc = 0; kc < 2; ++kc) {
      const int cx = (kc << 2) | l4;
      short8 ar[2], br[2];
#pragma unroll
      for (int m = 0; m < 2; ++m) {
        const int r = wm * 32 + m * 16 + l15;
        ar[m] = *(const short8*)(smem + cur + r * 128 + ((cx ^ (r & 7)) << 4));
      }
#pragma unroll
      for (int n = 0; n < 2; ++n) {
        const int r = wn * 32 + n * 16 + l15;
        br[n] = *(const short8*)(smem + cur + 16384 + r * 128 + ((cx ^ (r & 7)) << 4));
      }
#pragma unroll
      for (int m = 0; m < 2; ++m)
#pragma unroll
        for (int n = 0; n < 2; ++n) acc[m][n] = MFMA_BF16(ar[m], br[n], acc[m][n]);
    }
    __builtin_amdgcn_s_setprio(0);
  }
#pragma unroll
  for (int m = 0; m < 2; ++m)
#pragma unroll
    for (int n = 0; n < 2; ++n)
#pragma unroll
      for (int j = 0; j < 4; ++j)
        out[(size_t)(mbase + wm * 32 + m * 16 + l4 * 4 + j) * 768 + nbase + wn * 32 + n * 16 +
            l15] = acc[m][n][j];
}

extern "C" void kernel_launch(void* const* d_in, const int* in_sizes, int n_in, void* d_out,
                              int out_size, void* d_ws, size_t ws_size, hipStream_t stream) {
  (void)in_sizes;
  (void)n_in;
  (void)out_size;
  (void)ws_size;
  const float* query = (const float*)d_in[0];
  const float* key = (const float*)d_in[1];
  const float* value = (const float*)d_in[2];
  const float* Wq = (const float*)d_in[3];
  const float* Wk = (const float*)d_in[4];
  const float* Wv = (const float*)d_in[5];
  const float* Wo = (const float*)d_in[6];
  const float* s_v = (const float*)d_in[7];
  const float* s_r = (const float*)d_in[8];
  float* out = (float*)d_out;

  // ws layout (bf16 elems): [Xb 3x3145728 | Wb 4x589824 | qb | kb | vtb]
  // attn aliases Xb (dead after k_proj). Total 42.5 MB.
  unsigned short* cvt = (unsigned short*)d_ws;
  unsigned short* Xb = cvt;
  unsigned short* Wb = cvt + 9437184;
  unsigned short* qb = cvt + 11796480;
  unsigned short* kb = qb + 3145728;
  unsigned short* vtb = kb + 3145728;
  unsigned short* attn = cvt;

  k_cvt<<<5760, 256, 0, stream>>>(query, key, value, Wq, Wk, Wv, Wo, cvt);
  k_proj<<<dim3(32, 12, 3), 512, 0, stream>>>(Xb, Wb, qb, kb, vtb);
  k_attn<<<dim3(768), 512, 0, stream>>>(qb, kb, vtb, s_v, s_r, attn);
  k_outproj<<<dim3(32, 12), 512, 0, stream>>>(attn, Wb + 3 * 589824, out);
}